// Round 1
// baseline (323.099 us; speedup 1.0000x reference)
//
#include <hip/hip_runtime.h>
#include <hip/hip_bf16.h>

// Problem constants: B=2, N=2048, C=1024, H=16, hd=64, M=B*N=4096.
// Threshold is 2% of max|ref| -> bf16 MFMA compute path.

typedef __attribute__((ext_vector_type(8))) short short8;
typedef __attribute__((ext_vector_type(4))) float float4v;

__device__ __forceinline__ unsigned short f2bf(float f) {
    unsigned u = __builtin_bit_cast(unsigned, f);
    unsigned r = (u + 0x7FFFu + ((u >> 16) & 1u)) >> 16;
    return (unsigned short)r;
}

// ---------------- LayerNorm (f32 in) -> bf16 out, one block per 1024-wide row
__global__ __launch_bounds__(256) void ln_bf16(const float* __restrict__ x,
                                               const float* __restrict__ g,
                                               const float* __restrict__ bta,
                                               unsigned short* __restrict__ out) {
    const int row = blockIdx.x;
    const int tid = threadIdx.x;
    const float4* xr = reinterpret_cast<const float4*>(x + (size_t)row * 1024);
    float4 v = xr[tid];
    float s  = v.x + v.y + v.z + v.w;
    float sq = v.x * v.x + v.y * v.y + v.z * v.z + v.w * v.w;
#pragma unroll
    for (int off = 32; off >= 1; off >>= 1) {
        s  += __shfl_xor(s, off, 64);
        sq += __shfl_xor(sq, off, 64);
    }
    __shared__ float red[2][4];
    const int w = tid >> 6, lane = tid & 63;
    if (lane == 0) { red[0][w] = s; red[1][w] = sq; }
    __syncthreads();
    s  = red[0][0] + red[0][1] + red[0][2] + red[0][3];
    sq = red[1][0] + red[1][1] + red[1][2] + red[1][3];
    const float mu   = s * (1.f / 1024.f);
    const float var  = sq * (1.f / 1024.f) - mu * mu;
    const float rstd = rsqrtf(var + 1e-5f);
    const float4 gv = reinterpret_cast<const float4*>(g)[tid];
    const float4 bv = reinterpret_cast<const float4*>(bta)[tid];
    ushort4 o;
    o.x = f2bf((v.x - mu) * rstd * gv.x + bv.x);
    o.y = f2bf((v.y - mu) * rstd * gv.y + bv.y);
    o.z = f2bf((v.z - mu) * rstd * gv.z + bv.z);
    o.w = f2bf((v.w - mu) * rstd * gv.w + bv.w);
    *reinterpret_cast<ushort4*>(&out[(size_t)row * 1024 + tid * 4]) = o;
}

// ---------------- transpose + cast: in f32 [R][Cc] -> out bf16 [Cc][R]
__global__ __launch_bounds__(256) void transpose_cast(const float* __restrict__ in,
                                                      unsigned short* __restrict__ out,
                                                      int R, int Cc) {
    __shared__ float tile[32][33];
    const int c0 = blockIdx.x * 32, r0 = blockIdx.y * 32;
    const int tx = threadIdx.x, ty = threadIdx.y;
#pragma unroll
    for (int i = 0; i < 32; i += 8)
        tile[ty + i][tx] = in[(size_t)(r0 + ty + i) * Cc + c0 + tx];
    __syncthreads();
#pragma unroll
    for (int i = 0; i < 32; i += 8)
        out[(size_t)(c0 + ty + i) * R + r0 + tx] = f2bf(tile[tx][ty + i]);
}

// ---------------- shared 64x64 bf16 MFMA GEMM tile core (A[M,K] x Bt[N,K]^T)
// wave w owns rows w*16..w*16+15, all 64 cols (4 col-blocks of 16).
// LDS stride 72 (=+8 bf16 pad): row-to-row bank shift of 4 -> only 2-way
// aliasing on the b128 fragment reads (free per m136).
__device__ __forceinline__ void gemm_tile_acc(const unsigned short* __restrict__ A,
                                              const unsigned short* __restrict__ Bt,
                                              int K, int m0, int n0,
                                              unsigned short* As, unsigned short* Bs,
                                              float4v acc[4]) {
    const int tid = threadIdx.x;
    const int lane = tid & 63, w = tid >> 6;
    const int quad = lane >> 4, l16 = lane & 15;
#pragma unroll
    for (int cb = 0; cb < 4; cb++) acc[cb] = float4v{0.f, 0.f, 0.f, 0.f};
    for (int k0 = 0; k0 < K; k0 += 64) {
        __syncthreads();
#pragma unroll
        for (int p = 0; p < 2; p++) {
            const int idx = p * 256 + tid;
            const int row = idx >> 3, col8 = (idx & 7) << 3;
            *reinterpret_cast<uint4*>(&As[row * 72 + col8]) =
                *reinterpret_cast<const uint4*>(&A[(size_t)(m0 + row) * K + k0 + col8]);
            *reinterpret_cast<uint4*>(&Bs[row * 72 + col8]) =
                *reinterpret_cast<const uint4*>(&Bt[(size_t)(n0 + row) * K + k0 + col8]);
        }
        __syncthreads();
#pragma unroll
        for (int ks = 0; ks < 2; ks++) {
            short8 a = *reinterpret_cast<const short8*>(&As[(w * 16 + l16) * 72 + ks * 32 + quad * 8]);
#pragma unroll
            for (int cb = 0; cb < 4; cb++) {
                short8 b = *reinterpret_cast<const short8*>(&Bs[(cb * 16 + l16) * 72 + ks * 32 + quad * 8]);
                acc[cb] = __builtin_amdgcn_mfma_f32_16x16x32_bf16(a, b, acc[cb], 0, 0, 0);
            }
        }
    }
}

// ---------------- GEMM1: xn[4096,1024] @ [w_qk|w_v]^T -> scatter q/k/vT bf16
__global__ __launch_bounds__(256) void gemm_qkv(const unsigned short* __restrict__ A,
                                                const unsigned short* __restrict__ Bt,
                                                unsigned short* __restrict__ qb,
                                                unsigned short* __restrict__ kb,
                                                unsigned short* __restrict__ vT) {
    __shared__ unsigned short As[64 * 72], Bs[64 * 72];
    const int n0 = blockIdx.x * 64, m0 = blockIdx.y * 64;
    float4v acc[4];
    gemm_tile_acc(A, Bt, 1024, m0, n0, As, Bs, acc);
    const int lane = threadIdx.x & 63, w = threadIdx.x >> 6;
    const int quad = lane >> 4, l16 = lane & 15;
#pragma unroll
    for (int cb = 0; cb < 4; cb++) {
        const int gcol = n0 + cb * 16 + l16;
#pragma unroll
        for (int r = 0; r < 4; r++) {
            const int grow = m0 + w * 16 + quad * 4 + r;
            const int b = grow >> 11, nq = grow & 2047;
            const unsigned short bits = f2bf(acc[cb][r]);
            if (gcol < 1024) {            // q: [bh][n][d]
                const int h = gcol >> 6, d = gcol & 63;
                qb[(((size_t)b * 16 + h) * 2048 + nq) * 64 + d] = bits;
            } else if (gcol < 2048) {     // k: [bh][n][d]
                const int c = gcol - 1024, h = c >> 6, d = c & 63;
                kb[(((size_t)b * 16 + h) * 2048 + nq) * 64 + d] = bits;
            } else {                      // v transposed: [bh][d][n]
                const int c = gcol - 2048, h = c >> 6, d = c & 63;
                vT[(((size_t)b * 16 + h) * 64 + d) * 2048 + nq] = bits;
            }
        }
    }
}

// ---------------- GEMM2: y[4096,1024] @ w_proj^T + bias -> out f32
__global__ __launch_bounds__(256) void gemm_proj(const unsigned short* __restrict__ A,
                                                 const unsigned short* __restrict__ Bt,
                                                 const float* __restrict__ bias,
                                                 float* __restrict__ out) {
    __shared__ unsigned short As[64 * 72], Bs[64 * 72];
    const int n0 = blockIdx.x * 64, m0 = blockIdx.y * 64;
    float4v acc[4];
    gemm_tile_acc(A, Bt, 1024, m0, n0, As, Bs, acc);
    const int lane = threadIdx.x & 63, w = threadIdx.x >> 6;
    const int quad = lane >> 4, l16 = lane & 15;
#pragma unroll
    for (int cb = 0; cb < 4; cb++) {
        const int gcol = n0 + cb * 16 + l16;
        const float bv = bias[gcol];
#pragma unroll
        for (int r = 0; r < 4; r++) {
            const int grow = m0 + w * 16 + quad * 4 + r;
            out[(size_t)grow * 1024 + gcol] = acc[cb][r] + bv;
        }
    }
}

// ---------------- flash attention: Q-tile 64 rows/block (16/wave), K-tile 64
__global__ __launch_bounds__(256) void flash_attn(const unsigned short* __restrict__ qb,
                                                  const unsigned short* __restrict__ kb,
                                                  const unsigned short* __restrict__ vT,
                                                  float* __restrict__ attn) {
    __shared__ unsigned short Ks[64 * 72];      // K rows [key][c]
    __shared__ unsigned short Vs[64 * 72];      // V transposed [d][key]
    __shared__ unsigned short Ps[4][16 * 72];   // per-wave P C->A layout bounce
    const int tid = threadIdx.x, lane = tid & 63, w = tid >> 6;
    const int quad = lane >> 4, l16 = lane & 15;
    const int qt = blockIdx.x, bh = blockIdx.y;
    const int q0 = qt * 64;
    const size_t qbase = (size_t)bh * 2048;

    short8 aq[2];
#pragma unroll
    for (int ks = 0; ks < 2; ks++)
        aq[ks] = *reinterpret_cast<const short8*>(
            &qb[(qbase + q0 + w * 16 + l16) * 64 + ks * 32 + quad * 8]);

    float m_r[4], l_r[4];
    float4v o_acc[4];
#pragma unroll
    for (int r = 0; r < 4; r++) { m_r[r] = -INFINITY; l_r[r] = 0.f; }
#pragma unroll
    for (int cb = 0; cb < 4; cb++) o_acc[cb] = float4v{0.f, 0.f, 0.f, 0.f};
    const float scale = 0.125f;  // hd^-0.5

    for (int kt0 = 0; kt0 < 2048; kt0 += 64) {
        __syncthreads();
#pragma unroll
        for (int p = 0; p < 2; p++) {
            const int idx = p * 256 + tid;
            const int row = idx >> 3, col8 = (idx & 7) << 3;
            *reinterpret_cast<uint4*>(&Ks[row * 72 + col8]) =
                *reinterpret_cast<const uint4*>(&kb[(qbase + kt0 + row) * 64 + col8]);
            *reinterpret_cast<uint4*>(&Vs[row * 72 + col8]) =
                *reinterpret_cast<const uint4*>(&vT[((size_t)bh * 64 + row) * 2048 + kt0 + col8]);
        }
        __syncthreads();

        // S = Q K^T (16 q-rows x 64 keys per wave)
        float4v s_acc[4];
#pragma unroll
        for (int cb = 0; cb < 4; cb++) s_acc[cb] = float4v{0.f, 0.f, 0.f, 0.f};
#pragma unroll
        for (int ks = 0; ks < 2; ks++) {
#pragma unroll
            for (int cb = 0; cb < 4; cb++) {
                short8 b = *reinterpret_cast<const short8*>(
                    &Ks[(cb * 16 + l16) * 72 + ks * 32 + quad * 8]);
                s_acc[cb] = __builtin_amdgcn_mfma_f32_16x16x32_bf16(aq[ks], b, s_acc[cb], 0, 0, 0);
            }
        }

        // online softmax per q-row (row = quad*4 + r; 16 lanes hold 16 keys)
#pragma unroll
        for (int r = 0; r < 4; r++) {
            float s0 = s_acc[0][r] * scale, s1 = s_acc[1][r] * scale;
            float s2 = s_acc[2][r] * scale, s3 = s_acc[3][r] * scale;
            float mx = fmaxf(fmaxf(s0, s1), fmaxf(s2, s3));
#pragma unroll
            for (int off = 8; off >= 1; off >>= 1) mx = fmaxf(mx, __shfl_xor(mx, off, 64));
            const float m_new = fmaxf(m_r[r], mx);
            const float alpha = __expf(m_r[r] - m_new);
            m_r[r] = m_new;
            const float p0 = __expf(s0 - m_new), p1 = __expf(s1 - m_new);
            const float p2 = __expf(s2 - m_new), p3 = __expf(s3 - m_new);
            float rs = p0 + p1 + p2 + p3;
#pragma unroll
            for (int off = 8; off >= 1; off >>= 1) rs += __shfl_xor(rs, off, 64);
            l_r[r] = l_r[r] * alpha + rs;
#pragma unroll
            for (int cb = 0; cb < 4; cb++) o_acc[cb][r] *= alpha;
            const int prow = quad * 4 + r;
            Ps[w][prow * 72 +  0 + l16] = f2bf(p0);
            Ps[w][prow * 72 + 16 + l16] = f2bf(p1);
            Ps[w][prow * 72 + 32 + l16] = f2bf(p2);
            Ps[w][prow * 72 + 48 + l16] = f2bf(p3);
        }
        __syncthreads();  // order P writes (cross-lane) before A-layout reads

        // O += P V  (P from LDS in A-layout, V^T fragments contiguous)
#pragma unroll
        for (int kt = 0; kt < 2; kt++) {
            short8 pa = *reinterpret_cast<const short8*>(&Ps[w][l16 * 72 + kt * 32 + quad * 8]);
#pragma unroll
            for (int cb = 0; cb < 4; cb++) {
                short8 vb = *reinterpret_cast<const short8*>(
                    &Vs[(cb * 16 + l16) * 72 + kt * 32 + quad * 8]);
                o_acc[cb] = __builtin_amdgcn_mfma_f32_16x16x32_bf16(pa, vb, o_acc[cb], 0, 0, 0);
            }
        }
    }

    const int b = bh >> 4, h = bh & 15;
#pragma unroll
    for (int cb = 0; cb < 4; cb++) {
#pragma unroll
        for (int r = 0; r < 4; r++) {
            const int grow = b * 2048 + q0 + w * 16 + quad * 4 + r;
            const int gcol = h * 64 + cb * 16 + l16;
            attn[(size_t)grow * 1024 + gcol] = o_acc[cb][r] / l_r[r];
        }
    }
}

extern "C" void kernel_launch(void* const* d_in, const int* in_sizes, int n_in,
                              void* d_out, int out_size, void* d_ws, size_t ws_size,
                              hipStream_t stream) {
    const float* x      = (const float*)d_in[0];
    const float* ln1_g  = (const float*)d_in[1];
    const float* ln1_b  = (const float*)d_in[2];
    const float* w_qk   = (const float*)d_in[3];
    const float* w_v    = (const float*)d_in[4];
    const float* ln2_g  = (const float*)d_in[5];
    const float* ln2_b  = (const float*)d_in[6];
    const float* w_proj = (const float*)d_in[7];
    const float* b_proj = (const float*)d_in[8];
    float* out = (float*)d_out;

    char* ws = (char*)d_ws;
    // workspace layout (bytes), total 64 MB
    unsigned short* xn     = (unsigned short*)(ws + 0);         // 4096x1024 bf16 (8MB)
    unsigned short* wqkvT  = (unsigned short*)(ws + 8388608);   // 3072x1024 bf16 (6MB)
    unsigned short* wprojT = (unsigned short*)(ws + 14680064);  // 1024x1024 bf16 (2MB)
    unsigned short* qbuf   = (unsigned short*)(ws + 16777216);  // [32][2048][64] bf16 (8MB)
    unsigned short* kbuf   = (unsigned short*)(ws + 25165824);  // [32][2048][64] bf16 (8MB)
    unsigned short* vTbuf  = (unsigned short*)(ws + 33554432);  // [32][64][2048] bf16 (8MB)
    float*          attn   = (float*)(ws + 41943040);           // 4096x1024 f32 (16MB)
    unsigned short* ybuf   = (unsigned short*)(ws + 58720256);  // 4096x1024 bf16 (8MB)

    ln_bf16<<<4096, 256, 0, stream>>>(x, ln1_g, ln1_b, xn);
    transpose_cast<<<dim3(64, 32), dim3(32, 8), 0, stream>>>(w_qk, wqkvT, 1024, 2048);
    transpose_cast<<<dim3(32, 32), dim3(32, 8), 0, stream>>>(w_v, wqkvT + (size_t)2048 * 1024, 1024, 1024);
    transpose_cast<<<dim3(32, 32), dim3(32, 8), 0, stream>>>(w_proj, wprojT, 1024, 1024);
    gemm_qkv<<<dim3(48, 64), 256, 0, stream>>>(xn, wqkvT, qbuf, kbuf, vTbuf);
    flash_attn<<<dim3(32, 32), 256, 0, stream>>>(qbuf, kbuf, vTbuf, attn);
    ln_bf16<<<4096, 256, 0, stream>>>(attn, ln2_g, ln2_b, ybuf);
    gemm_proj<<<dim3(16, 64), 256, 0, stream>>>(ybuf, wprojT, b_proj, out);
}

// Round 2
// 269.259 us; speedup vs baseline: 1.2000x; 1.2000x over previous
//
#include <hip/hip_runtime.h>
#include <hip/hip_bf16.h>

// B=2, N=2048, C=1024, H=16, hd=64, M=4096. bf16 MFMA path (threshold 2%).

typedef __attribute__((ext_vector_type(8))) short short8;
typedef __attribute__((ext_vector_type(4))) short short4v;
typedef __attribute__((ext_vector_type(4))) float float4v;

__device__ __forceinline__ unsigned short f2bf(float f) {   // RTNE
    unsigned u = __builtin_bit_cast(unsigned, f);
    return (unsigned short)((u + 0x7FFFu + ((u >> 16) & 1u)) >> 16);
}
__device__ __forceinline__ short bf16r(float f) {           // fast round
    return (short)((__builtin_bit_cast(unsigned, f) + 0x8000u) >> 16);
}
__device__ __forceinline__ void gll16(const unsigned short* g, unsigned short* l) {
    __builtin_amdgcn_global_load_lds(
        (const __attribute__((address_space(1))) unsigned int*)g,
        (__attribute__((address_space(3))) unsigned int*)l, 16, 0, 0);
}

// ---------------- LayerNorm (f32 in) -> bf16 out, one block per 1024-wide row
__global__ __launch_bounds__(256) void ln_bf16(const float* __restrict__ x,
                                               const float* __restrict__ g,
                                               const float* __restrict__ bta,
                                               unsigned short* __restrict__ out) {
    const int row = blockIdx.x;
    const int tid = threadIdx.x;
    const float4* xr = reinterpret_cast<const float4*>(x + (size_t)row * 1024);
    float4 v = xr[tid];
    float s  = v.x + v.y + v.z + v.w;
    float sq = v.x * v.x + v.y * v.y + v.z * v.z + v.w * v.w;
#pragma unroll
    for (int off = 32; off >= 1; off >>= 1) {
        s  += __shfl_xor(s, off, 64);
        sq += __shfl_xor(sq, off, 64);
    }
    __shared__ float red[2][4];
    const int w = tid >> 6, lane = tid & 63;
    if (lane == 0) { red[0][w] = s; red[1][w] = sq; }
    __syncthreads();
    s  = red[0][0] + red[0][1] + red[0][2] + red[0][3];
    sq = red[1][0] + red[1][1] + red[1][2] + red[1][3];
    const float mu   = s * (1.f / 1024.f);
    const float var  = sq * (1.f / 1024.f) - mu * mu;
    const float rstd = rsqrtf(var + 1e-5f);
    const float4 gv = reinterpret_cast<const float4*>(g)[tid];
    const float4 bv = reinterpret_cast<const float4*>(bta)[tid];
    ushort4 o;
    o.x = f2bf((v.x - mu) * rstd * gv.x + bv.x);
    o.y = f2bf((v.y - mu) * rstd * gv.y + bv.y);
    o.z = f2bf((v.z - mu) * rstd * gv.z + bv.z);
    o.w = f2bf((v.w - mu) * rstd * gv.w + bv.w);
    *reinterpret_cast<ushort4*>(&out[(size_t)row * 1024 + tid * 4]) = o;
}

// ---------------- transpose + cast: in f32 [R][Cc] -> out bf16 [Cc][R]
__global__ __launch_bounds__(256) void transpose_cast(const float* __restrict__ in,
                                                      unsigned short* __restrict__ out,
                                                      int R, int Cc) {
    __shared__ float tile[32][33];
    const int c0 = blockIdx.x * 32, r0 = blockIdx.y * 32;
    const int tx = threadIdx.x, ty = threadIdx.y;
#pragma unroll
    for (int i = 0; i < 32; i += 8)
        tile[ty + i][tx] = in[(size_t)(r0 + ty + i) * Cc + c0 + tx];
    __syncthreads();
#pragma unroll
    for (int i = 0; i < 32; i += 8)
        out[(size_t)(c0 + ty + i) * R + r0 + tx] = f2bf(tile[tx][ty + i]);
}

// ---------------- 128x128 MFMA GEMM core (m97-style): A[M,K] x Bt[N,K]^T.
// global_load_lds width-16 staging into XOR-swizzled LDS [128][64]:
// element (row, group g) lives at row*64 + (g ^ (row&7))*8. Swizzle applied
// via the GLOBAL address (LDS dst is wave-base + lane*16, fixed order).
// Fragment b128 reads are then bank-conflict-free.
__device__ __forceinline__ void gemm128_core(const unsigned short* __restrict__ A,
                                             const unsigned short* __restrict__ Bt,
                                             int K, int m0, int n0,
                                             unsigned short* As, unsigned short* Bs,
                                             float4v acc[4][4]) {
    const int tid = threadIdx.x, lane = tid & 63, w = tid >> 6;
    const int wr = (w >> 1) * 64, wc = (w & 1) * 64;
    const int quad = lane >> 4, l16 = lane & 15;
    const int ls = lane >> 3, sg = lane & 7;
#pragma unroll
    for (int mi = 0; mi < 4; mi++)
#pragma unroll
        for (int ni = 0; ni < 4; ni++) acc[mi][ni] = float4v{0.f, 0.f, 0.f, 0.f};

    for (int k0 = 0; k0 < K; k0 += 64) {
        __syncthreads();
#pragma unroll
        for (int i = 0; i < 4; i++) {
            const int r = w * 32 + i * 8 + ls;          // r&7 == ls
            const int g = (sg ^ ls) * 8;
            gll16(&A[(size_t)(m0 + r) * K + k0 + g], &As[(w * 32 + i * 8) * 64]);
            gll16(&Bt[(size_t)(n0 + r) * K + k0 + g], &Bs[(w * 32 + i * 8) * 64]);
        }
        __syncthreads();
#pragma unroll
        for (int ks = 0; ks < 2; ks++) {
            short8 af[4], bfr[4];
#pragma unroll
            for (int mi = 0; mi < 4; mi++) {
                const int r = wr + mi * 16 + l16;       // r&7 == l16&7
                af[mi] = *reinterpret_cast<const short8*>(
                    &As[r * 64 + ((ks * 4 + quad) ^ (r & 7)) * 8]);
            }
#pragma unroll
            for (int ni = 0; ni < 4; ni++) {
                const int r = wc + ni * 16 + l16;
                bfr[ni] = *reinterpret_cast<const short8*>(
                    &Bs[r * 64 + ((ks * 4 + quad) ^ (r & 7)) * 8]);
            }
#pragma unroll
            for (int mi = 0; mi < 4; mi++)
#pragma unroll
                for (int ni = 0; ni < 4; ni++)
                    acc[mi][ni] = __builtin_amdgcn_mfma_f32_16x16x32_bf16(
                        af[mi], bfr[ni], acc[mi][ni], 0, 0, 0);
        }
    }
}

// ---------------- GEMM1: xn @ [w_qk|w_v]^T -> scatter q (pre-scaled), k, vT
__global__ __launch_bounds__(256) void gemm128_qkv(const unsigned short* __restrict__ A,
                                                   const unsigned short* __restrict__ Bt,
                                                   unsigned short* __restrict__ qb,
                                                   unsigned short* __restrict__ kb,
                                                   unsigned short* __restrict__ vT) {
    __shared__ unsigned short As[128 * 64], Bs[128 * 64];
    const int m0 = blockIdx.y * 128, n0 = blockIdx.x * 128;
    float4v acc[4][4];
    gemm128_core(A, Bt, 1024, m0, n0, As, Bs, acc);
    const int lane = threadIdx.x & 63, w = threadIdx.x >> 6;
    const int wr = (w >> 1) * 64, wc = (w & 1) * 64;
    const int quad = lane >> 4, l16 = lane & 15;
    const float QSCALE = 0.125f * 1.4426950408889634f;  // hd^-0.5 * log2(e)
#pragma unroll
    for (int mi = 0; mi < 4; mi++) {
#pragma unroll
        for (int ni = 0; ni < 4; ni++) {
            const int col = n0 + wc + ni * 16 + l16;
#pragma unroll
            for (int r = 0; r < 4; r++) {
                const int row = m0 + wr + mi * 16 + quad * 4 + r;
                const int b = row >> 11, nq = row & 2047;
                const float v = acc[mi][ni][r];
                if (col < 1024) {             // q: [bh][n][d], scale folded
                    const int h = col >> 6, d = col & 63;
                    qb[(((size_t)b * 16 + h) * 2048 + nq) * 64 + d] = f2bf(v * QSCALE);
                } else if (col < 2048) {      // k: [bh][n][d]
                    const int c = col - 1024, h = c >> 6, d = c & 63;
                    kb[(((size_t)b * 16 + h) * 2048 + nq) * 64 + d] = f2bf(v);
                } else {                      // v transposed: [bh][d][n]
                    const int c = col - 2048, h = c >> 6, d = c & 63;
                    vT[(((size_t)b * 16 + h) * 64 + d) * 2048 + nq] = f2bf(v);
                }
            }
        }
    }
}

// ---------------- GEMM2: y @ w_proj^T + bias -> out f32
__global__ __launch_bounds__(256) void gemm128_proj(const unsigned short* __restrict__ A,
                                                    const unsigned short* __restrict__ Bt,
                                                    const float* __restrict__ bias,
                                                    float* __restrict__ out) {
    __shared__ unsigned short As[128 * 64], Bs[128 * 64];
    const int m0 = blockIdx.y * 128, n0 = blockIdx.x * 128;
    float4v acc[4][4];
    gemm128_core(A, Bt, 1024, m0, n0, As, Bs, acc);
    const int lane = threadIdx.x & 63, w = threadIdx.x >> 6;
    const int wr = (w >> 1) * 64, wc = (w & 1) * 64;
    const int quad = lane >> 4, l16 = lane & 15;
#pragma unroll
    for (int mi = 0; mi < 4; mi++) {
#pragma unroll
        for (int ni = 0; ni < 4; ni++) {
            const int col = n0 + wc + ni * 16 + l16;
            const float bv = bias[col];
#pragma unroll
            for (int r = 0; r < 4; r++) {
                const int row = m0 + wr + mi * 16 + quad * 4 + r;
                out[(size_t)row * 1024 + col] = acc[mi][ni][r] + bv;
            }
        }
    }
}

// ---------------- flash attention, S^T formulation (no P LDS round-trip).
// S^T = K·Q^T via mfma(K as A, Q as B): C-layout gives lane 16 scores for
// q = lane&15, keys cb*16 + quad*4 + reg. That register layout IS the
// A-operand layout of mfma_f32_16x16x16_bf16 (k = quad*4+j), so P feeds the
// PV mfma directly from registers. Q pre-scaled by 0.125*log2e -> exp2.
__global__ __launch_bounds__(256) void flash_attn(const unsigned short* __restrict__ qb,
                                                  const unsigned short* __restrict__ kb,
                                                  const unsigned short* __restrict__ vT,
                                                  float* __restrict__ attn) {
    __shared__ unsigned short Ks[64 * 72];   // [key][d]
    __shared__ unsigned short Vs[64 * 72];   // [d][key]
    const int tid = threadIdx.x, lane = tid & 63, w = tid >> 6;
    const int quad = lane >> 4, l16 = lane & 15;
    const int qt = blockIdx.x, bh = blockIdx.y;
    const int q0 = qt * 64;
    const size_t qbase = (size_t)bh * 2048;

    short8 bq[2];  // Q as B-operand: B[n=q=lane&15][k=quad*8+j]
#pragma unroll
    for (int ks = 0; ks < 2; ks++)
        bq[ks] = *reinterpret_cast<const short8*>(
            &qb[(qbase + q0 + w * 16 + l16) * 64 + ks * 32 + quad * 8]);

    float m_prev = -INFINITY, l_run = 0.f;
    float4v o_acc[4];  // db: O[q=quad*4+reg][d=db*16+l16]
#pragma unroll
    for (int db = 0; db < 4; db++) o_acc[db] = float4v{0.f, 0.f, 0.f, 0.f};

    for (int kt0 = 0; kt0 < 2048; kt0 += 64) {
        __syncthreads();
#pragma unroll
        for (int p = 0; p < 2; p++) {
            const int idx = p * 256 + tid;
            const int row = idx >> 3, col8 = (idx & 7) << 3;
            *reinterpret_cast<uint4*>(&Ks[row * 72 + col8]) =
                *reinterpret_cast<const uint4*>(&kb[(qbase + kt0 + row) * 64 + col8]);
            *reinterpret_cast<uint4*>(&Vs[row * 72 + col8]) =
                *reinterpret_cast<const uint4*>(&vT[((size_t)bh * 64 + row) * 2048 + kt0 + col8]);
        }
        __syncthreads();

        // S^T tiles: s_acc[cb][reg] = S[q=l16][key = cb*16 + quad*4 + reg]
        float4v s_acc[4];
#pragma unroll
        for (int cb = 0; cb < 4; cb++) s_acc[cb] = float4v{0.f, 0.f, 0.f, 0.f};
#pragma unroll
        for (int ks = 0; ks < 2; ks++) {
#pragma unroll
            for (int cb = 0; cb < 4; cb++) {
                short8 kf = *reinterpret_cast<const short8*>(
                    &Ks[(cb * 16 + l16) * 72 + ks * 32 + quad * 8]);
                s_acc[cb] = __builtin_amdgcn_mfma_f32_16x16x32_bf16(kf, bq[ks], s_acc[cb], 0, 0, 0);
            }
        }

        // online softmax for q=l16 over this tile's 64 keys (log2 domain)
        float mx = s_acc[0][0];
#pragma unroll
        for (int cb = 0; cb < 4; cb++)
#pragma unroll
            for (int r = 0; r < 4; r++) mx = fmaxf(mx, s_acc[cb][r]);
        mx = fmaxf(mx, __shfl_xor(mx, 16, 64));
        mx = fmaxf(mx, __shfl_xor(mx, 32, 64));
        const float m_new = fmaxf(m_prev, mx);
        const float alpha = __builtin_amdgcn_exp2f(m_prev - m_new);
        m_prev = m_new;
        float p_v[4][4];
        float rs = 0.f;
#pragma unroll
        for (int cb = 0; cb < 4; cb++)
#pragma unroll
            for (int r = 0; r < 4; r++) {
                const float pv = __builtin_amdgcn_exp2f(s_acc[cb][r] - m_new);
                p_v[cb][r] = pv;
                rs += pv;
            }
        rs += __shfl_xor(rs, 16, 64);
        rs += __shfl_xor(rs, 32, 64);
        l_run = l_run * alpha + rs;

        // rescale O rows (q = quad*4+r needs alpha from lane quad*4+r)
#pragma unroll
        for (int r = 0; r < 4; r++) {
            const float a_r = __shfl(alpha, quad * 4 + r, 64);
#pragma unroll
            for (int db = 0; db < 4; db++) o_acc[db][r] *= a_r;
        }

        // O += P V : A = P (direct from registers), B = V^T b64 fragments
#pragma unroll
        for (int kt = 0; kt < 4; kt++) {
            const short4v pa = {bf16r(p_v[kt][0]), bf16r(p_v[kt][1]),
                                bf16r(p_v[kt][2]), bf16r(p_v[kt][3])};
#pragma unroll
            for (int db = 0; db < 4; db++) {
                const short4v vb = *reinterpret_cast<const short4v*>(
                    &Vs[(db * 16 + l16) * 72 + kt * 16 + quad * 4]);
                o_acc[db] = __builtin_amdgcn_mfma_f32_16x16x16bf16_1k(pa, vb, o_acc[db], 0, 0, 0);
            }
        }
    }

    const int b = bh >> 4, h = bh & 15;
#pragma unroll
    for (int r = 0; r < 4; r++) {
        const float l_r = __shfl(l_run, quad * 4 + r, 64);
        const float inv = __builtin_amdgcn_rcpf(l_r);
        const int grow = b * 2048 + q0 + w * 16 + quad * 4 + r;
#pragma unroll
        for (int db = 0; db < 4; db++) {
            const int gcol = h * 64 + db * 16 + l16;
            attn[(size_t)grow * 1024 + gcol] = o_acc[db][r] * inv;
        }
    }
}

extern "C" void kernel_launch(void* const* d_in, const int* in_sizes, int n_in,
                              void* d_out, int out_size, void* d_ws, size_t ws_size,
                              hipStream_t stream) {
    const float* x      = (const float*)d_in[0];
    const float* ln1_g  = (const float*)d_in[1];
    const float* ln1_b  = (const float*)d_in[2];
    const float* w_qk   = (const float*)d_in[3];
    const float* w_v    = (const float*)d_in[4];
    const float* ln2_g  = (const float*)d_in[5];
    const float* ln2_b  = (const float*)d_in[6];
    const float* w_proj = (const float*)d_in[7];
    const float* b_proj = (const float*)d_in[8];
    float* out = (float*)d_out;

    char* ws = (char*)d_ws;
    unsigned short* xn     = (unsigned short*)(ws + 0);         // 4096x1024 bf16 (8MB)
    unsigned short* wqkvT  = (unsigned short*)(ws + 8388608);   // 3072x1024 bf16 (6MB)
    unsigned short* wprojT = (unsigned short*)(ws + 14680064);  // 1024x1024 bf16 (2MB)
    unsigned short* qbuf   = (unsigned short*)(ws + 16777216);  // [32][2048][64] (8MB)
    unsigned short* kbuf   = (unsigned short*)(ws + 25165824);  // [32][2048][64] (8MB)
    unsigned short* vTbuf  = (unsigned short*)(ws + 33554432);  // [32][64][2048] (8MB)
    float*          attn   = (float*)(ws + 41943040);           // 4096x1024 f32 (16MB)
    unsigned short* ybuf   = (unsigned short*)(ws + 58720256);  // 4096x1024 bf16 (8MB)

    ln_bf16<<<4096, 256, 0, stream>>>(x, ln1_g, ln1_b, xn);
    transpose_cast<<<dim3(64, 32), dim3(32, 8), 0, stream>>>(w_qk, wqkvT, 1024, 2048);
    transpose_cast<<<dim3(32, 32), dim3(32, 8), 0, stream>>>(w_v, wqkvT + (size_t)2048 * 1024, 1024, 1024);
    transpose_cast<<<dim3(32, 32), dim3(32, 8), 0, stream>>>(w_proj, wprojT, 1024, 1024);
    gemm128_qkv<<<dim3(24, 32), 256, 0, stream>>>(xn, wqkvT, qbuf, kbuf, vTbuf);
    flash_attn<<<dim3(32, 32), 256, 0, stream>>>(qbuf, kbuf, vTbuf, attn);
    ln_bf16<<<4096, 256, 0, stream>>>(attn, ln2_g, ln2_b, ybuf);
    gemm128_proj<<<dim3(8, 32), 256, 0, stream>>>(ybuf, wprojT, b_proj, out);
}

// Round 3
// 251.222 us; speedup vs baseline: 1.2861x; 1.0718x over previous
//
#include <hip/hip_runtime.h>
#include <hip/hip_bf16.h>

// B=2, N=2048, C=1024, H=16, hd=64, M=4096. bf16 MFMA path (threshold 2%).

typedef __attribute__((ext_vector_type(8))) short short8;
typedef __attribute__((ext_vector_type(4))) short short4v;
typedef __attribute__((ext_vector_type(4))) float float4v;

__device__ __forceinline__ unsigned short f2bf(float f) {   // RTNE
    unsigned u = __builtin_bit_cast(unsigned, f);
    return (unsigned short)((u + 0x7FFFu + ((u >> 16) & 1u)) >> 16);
}
// pack two f32 -> two bf16 (round-half-up) in one dword via v_perm
__device__ __forceinline__ unsigned packbf2(float lo, float hi) {
    return __builtin_amdgcn_perm(__builtin_bit_cast(unsigned, hi) + 0x8000u,
                                 __builtin_bit_cast(unsigned, lo) + 0x8000u,
                                 0x07060302u);
}
__device__ __forceinline__ void gll16(const unsigned short* g, unsigned short* l) {
    __builtin_amdgcn_global_load_lds(
        (const __attribute__((address_space(1))) unsigned int*)g,
        (__attribute__((address_space(3))) unsigned int*)l, 16, 0, 0);
}

// ---------------- prep: ln1 (blocks 0..4095) + weight transposes + u/w0 vectors
__global__ __launch_bounds__(256) void prep(
    const float* __restrict__ x, const float* __restrict__ g1, const float* __restrict__ b1,
    const float* __restrict__ w_qk, const float* __restrict__ w_v,
    const float* __restrict__ w_proj, const float* __restrict__ g2,
    const float* __restrict__ b2, const float* __restrict__ b_proj,
    unsigned short* __restrict__ xn, unsigned short* __restrict__ wqkvT,
    unsigned short* __restrict__ wgT, float* __restrict__ u, float* __restrict__ w0) {
    __shared__ float sh[32 * 33];
    const int bid = blockIdx.x, tid = threadIdx.x;
    if (bid < 4096) {                       // ---- LN1 row
        const float4 v = reinterpret_cast<const float4*>(x + (size_t)bid * 1024)[tid];
        float s  = v.x + v.y + v.z + v.w;
        float sq = v.x * v.x + v.y * v.y + v.z * v.z + v.w * v.w;
#pragma unroll
        for (int off = 32; off >= 1; off >>= 1) {
            s  += __shfl_xor(s, off, 64);
            sq += __shfl_xor(sq, off, 64);
        }
        const int w = tid >> 6, lane = tid & 63;
        if (lane == 0) { sh[w] = s; sh[4 + w] = sq; }
        __syncthreads();
        s  = sh[0] + sh[1] + sh[2] + sh[3];
        sq = sh[4] + sh[5] + sh[6] + sh[7];
        const float mu = s * (1.f / 1024.f);
        const float rstd = rsqrtf(sq * (1.f / 1024.f) - mu * mu + 1e-5f);
        const float4 gv = reinterpret_cast<const float4*>(g1)[tid];
        const float4 bv = reinterpret_cast<const float4*>(b1)[tid];
        ushort4 o;
        o.x = f2bf((v.x - mu) * rstd * gv.x + bv.x);
        o.y = f2bf((v.y - mu) * rstd * gv.y + bv.y);
        o.z = f2bf((v.z - mu) * rstd * gv.z + bv.z);
        o.w = f2bf((v.w - mu) * rstd * gv.w + bv.w);
        *reinterpret_cast<ushort4*>(&xn[(size_t)bid * 1024 + tid * 4]) = o;
    } else if (bid < 8192) {                // ---- transpose f32[1024][Cc] -> bf16[Cc][1024]
        const float* in; unsigned short* out; int Cc, bx, by; const float* sc = nullptr;
        if (bid < 6144)      { int t = bid - 4096; in = w_qk;   out = wqkvT;                 Cc = 2048; bx = t & 63; by = t >> 6; }
        else if (bid < 7168) { int t = bid - 6144; in = w_v;    out = wqkvT + 2048 * 1024;   Cc = 1024; bx = t & 31; by = t >> 5; }
        else                 { int t = bid - 7168; in = w_proj; out = wgT; sc = g2;          Cc = 1024; bx = t & 31; by = t >> 5; }
        const int c0 = bx * 32, r0 = by * 32;
        const int tx = tid & 31, ty = tid >> 5;
#pragma unroll
        for (int i = 0; i < 32; i += 8)
            sh[(ty + i) * 33 + tx] = in[(size_t)(r0 + ty + i) * Cc + c0 + tx];
        __syncthreads();
        const float scale = sc ? sc[r0 + tx] : 1.f;   // out-col = in-row index
#pragma unroll
        for (int i = 0; i < 32; i += 8)
            out[(size_t)(c0 + ty + i) * 1024 + r0 + tx] = f2bf(sh[tx * 33 + ty + i] * scale);
    } else {                                // ---- u[j] = sum_c g2[c]*Wp[c][j]; w0[j] = b2@Wp + b_proj
        const int j = (bid - 8192) * 256 + tid;
        float ua = 0.f, wa = 0.f;
        for (int c = 0; c < 1024; c++) {
            const float wp = w_proj[(size_t)c * 1024 + j];
            ua = fmaf(g2[c], wp, ua);
            wa = fmaf(b2[c], wp, wa);
        }
        u[j]  = ua;
        w0[j] = wa + b_proj[j];
    }
}

// ---------------- 128x128 MFMA GEMM core (m97-style): A[M,K] x Bt[N,K]^T.
// global_load_lds width-16 staging into XOR-swizzled LDS [128][64].
__device__ __forceinline__ void gemm128_core(const unsigned short* __restrict__ A,
                                             const unsigned short* __restrict__ Bt,
                                             int K, int m0, int n0,
                                             unsigned short* As, unsigned short* Bs,
                                             float4v acc[4][4]) {
    const int tid = threadIdx.x, lane = tid & 63, w = tid >> 6;
    const int wr = (w >> 1) * 64, wc = (w & 1) * 64;
    const int quad = lane >> 4, l16 = lane & 15;
    const int ls = lane >> 3, sg = lane & 7;
#pragma unroll
    for (int mi = 0; mi < 4; mi++)
#pragma unroll
        for (int ni = 0; ni < 4; ni++) acc[mi][ni] = float4v{0.f, 0.f, 0.f, 0.f};

    for (int k0 = 0; k0 < K; k0 += 64) {
        __syncthreads();
#pragma unroll
        for (int i = 0; i < 4; i++) {
            const int r = w * 32 + i * 8 + ls;          // r&7 == ls
            const int g = (sg ^ ls) * 8;
            gll16(&A[(size_t)(m0 + r) * K + k0 + g], &As[(w * 32 + i * 8) * 64]);
            gll16(&Bt[(size_t)(n0 + r) * K + k0 + g], &Bs[(w * 32 + i * 8) * 64]);
        }
        __syncthreads();
#pragma unroll
        for (int ks = 0; ks < 2; ks++) {
            short8 af[4], bfr[4];
#pragma unroll
            for (int mi = 0; mi < 4; mi++) {
                const int r = wr + mi * 16 + l16;
                af[mi] = *reinterpret_cast<const short8*>(
                    &As[r * 64 + ((ks * 4 + quad) ^ (r & 7)) * 8]);
            }
#pragma unroll
            for (int ni = 0; ni < 4; ni++) {
                const int r = wc + ni * 16 + l16;
                bfr[ni] = *reinterpret_cast<const short8*>(
                    &Bs[r * 64 + ((ks * 4 + quad) ^ (r & 7)) * 8]);
            }
#pragma unroll
            for (int mi = 0; mi < 4; mi++)
#pragma unroll
                for (int ni = 0; ni < 4; ni++)
                    acc[mi][ni] = __builtin_amdgcn_mfma_f32_16x16x32_bf16(
                        af[mi], bfr[ni], acc[mi][ni], 0, 0, 0);
        }
    }
}

// ---------------- GEMM1: xn @ [w_qk|w_v]^T -> q (pre-scaled by 1/8*log2e), k, vT
__global__ __launch_bounds__(256) void gemm128_qkv(const unsigned short* __restrict__ A,
                                                   const unsigned short* __restrict__ Bt,
                                                   unsigned short* __restrict__ qb,
                                                   unsigned short* __restrict__ kb,
                                                   unsigned short* __restrict__ vT) {
    __shared__ unsigned short As[128 * 64], Bs[128 * 64];
    const int m0 = blockIdx.y * 128, n0 = blockIdx.x * 128;
    float4v acc[4][4];
    gemm128_core(A, Bt, 1024, m0, n0, As, Bs, acc);
    const int lane = threadIdx.x & 63, w = threadIdx.x >> 6;
    const int wr = (w >> 1) * 64, wc = (w & 1) * 64;
    const int quad = lane >> 4, l16 = lane & 15;
    const float QSCALE = 0.125f * 1.4426950408889634f;  // hd^-0.5 * log2(e)
#pragma unroll
    for (int mi = 0; mi < 4; mi++) {
        const int row0 = m0 + wr + mi * 16 + quad * 4;
        const int b = row0 >> 11, nq = row0 & 2047;
#pragma unroll
        for (int ni = 0; ni < 4; ni++) {
            const int col = n0 + wc + ni * 16 + l16;
            if (col < 1024) {             // q: [bh][n][d]
                const int h = col >> 6, d = col & 63;
#pragma unroll
                for (int r = 0; r < 4; r++)
                    qb[(((size_t)b * 16 + h) * 2048 + nq + r) * 64 + d] =
                        f2bf(acc[mi][ni][r] * QSCALE);
            } else if (col < 2048) {      // k: [bh][n][d]
                const int c = col - 1024, h = c >> 6, d = c & 63;
#pragma unroll
                for (int r = 0; r < 4; r++)
                    kb[(((size_t)b * 16 + h) * 2048 + nq + r) * 64 + d] = f2bf(acc[mi][ni][r]);
            } else {                      // v^T: [bh][d][n], 4 consecutive keys -> 8B store
                const int c = col - 2048, h = c >> 6, d = c & 63;
                const short4v sv = {(short)f2bf(acc[mi][ni][0]), (short)f2bf(acc[mi][ni][1]),
                                    (short)f2bf(acc[mi][ni][2]), (short)f2bf(acc[mi][ni][3])};
                *reinterpret_cast<short4v*>(
                    &vT[(((size_t)b * 16 + h) * 64 + d) * 2048 + nq]) = sv;
            }
        }
    }
}

// ---------------- flash attention v3: Q-tile 128 (32 q/wave), fixed-max softmax,
// S^T formulation, zero in-loop shuffles, swizzled conflict-free LDS.
// Outputs attn in bf16 + per-(row,head) (sum, sumsq) partials for fused LN2.
__global__ __launch_bounds__(256) void flash_attn(const unsigned short* __restrict__ qbuf,
                                                  const unsigned short* __restrict__ kb,
                                                  const unsigned short* __restrict__ vT,
                                                  unsigned short* __restrict__ attn,
                                                  float2* __restrict__ part) {
    __shared__ unsigned short Ks[64 * 64];   // [key][d], XOR-swizzled 16B granules
    __shared__ unsigned short Vs[64 * 64];   // [d][key], XOR-swizzled 8B granules
    const int tid = threadIdx.x, lane = tid & 63, w = tid >> 6;
    const int quad = lane >> 4, l16 = lane & 15;
    const int ls = lane >> 3, sg = lane & 7;
    const int qt = blockIdx.x, bh = blockIdx.y;
    const int q0 = qt * 128;
    const size_t nbase = (size_t)bh * 2048;

    short8 bq[2][2];   // Q as B-operand for two 16-q subblocks
#pragma unroll
    for (int q2 = 0; q2 < 2; q2++)
#pragma unroll
        for (int ks = 0; ks < 2; ks++)
            bq[q2][ks] = *reinterpret_cast<const short8*>(
                &qbuf[(nbase + q0 + w * 32 + q2 * 16 + l16) * 64 + ks * 32 + quad * 8]);

    float l_part[2] = {0.f, 0.f};
    float4v o_acc[2][4];
#pragma unroll
    for (int q2 = 0; q2 < 2; q2++)
#pragma unroll
        for (int db = 0; db < 4; db++) o_acc[q2][db] = float4v{0.f, 0.f, 0.f, 0.f};

    for (int kt0 = 0; kt0 < 2048; kt0 += 64) {
        __syncthreads();
        // K tile via global_load_lds (swizzled source -> swizzled LDS rows)
#pragma unroll
        for (int i = 0; i < 2; i++)
            gll16(&kb[(nbase + kt0 + w * 16 + i * 8 + ls) * 64 + ((sg ^ ls) << 3)],
                  &Ks[(w * 16 + i * 8) * 64]);
        // V tile: vT rows -> Vs[d][key] with 8B-granule swizzle (key>>2)^(d&15)
#pragma unroll
        for (int p = 0; p < 2; p++) {
            const int idx2 = p * 256 + tid;
            const int d = idx2 >> 3, G0 = (idx2 & 7) * 2;
            const uint4 vv = *reinterpret_cast<const uint4*>(
                &vT[((size_t)bh * 64 + d) * 2048 + kt0 + (G0 << 2)]);
            *reinterpret_cast<short4v*>(&Vs[(d << 6) + ((G0 ^ (d & 15)) << 2)]) =
                __builtin_bit_cast(short4v, uint2{vv.x, vv.y});
            *reinterpret_cast<short4v*>(&Vs[(d << 6) + (((G0 + 1) ^ (d & 15)) << 2)]) =
                __builtin_bit_cast(short4v, uint2{vv.z, vv.w});
        }
        __syncthreads();

        short8 kf[2][4];
#pragma unroll
        for (int ks = 0; ks < 2; ks++)
#pragma unroll
            for (int cb = 0; cb < 4; cb++) {
                const int r = cb * 16 + l16;
                kf[ks][cb] = *reinterpret_cast<const short8*>(
                    &Ks[r * 64 + ((ks * 4 + quad) ^ (r & 7)) * 8]);
            }
        short4v vb[4][4];
#pragma unroll
        for (int kt = 0; kt < 4; kt++)
#pragma unroll
            for (int db = 0; db < 4; db++)
                vb[kt][db] = *reinterpret_cast<const short4v*>(
                    &Vs[((db * 16 + l16) << 6) + (((kt * 4 + quad) ^ l16) << 2)]);

#pragma unroll
        for (int q2 = 0; q2 < 2; q2++) {
            float4v s_acc[4];
#pragma unroll
            for (int cb = 0; cb < 4; cb++) s_acc[cb] = float4v{0.f, 0.f, 0.f, 0.f};
#pragma unroll
            for (int ks = 0; ks < 2; ks++)
#pragma unroll
                for (int cb = 0; cb < 4; cb++)
                    s_acc[cb] = __builtin_amdgcn_mfma_f32_16x16x32_bf16(
                        kf[ks][cb], bq[q2][ks], s_acc[cb], 0, 0, 0);

            // fixed-max softmax: p = 2^s (s hard-bounded ~ +-12, no overflow; O/l cancels)
            short4v pa[4];
            float ls2 = 0.f;
#pragma unroll
            for (int cb = 0; cb < 4; cb++) {
                const float p0 = __builtin_amdgcn_exp2f(s_acc[cb][0]);
                const float p1 = __builtin_amdgcn_exp2f(s_acc[cb][1]);
                const float p2 = __builtin_amdgcn_exp2f(s_acc[cb][2]);
                const float p3 = __builtin_amdgcn_exp2f(s_acc[cb][3]);
                ls2 += (p0 + p1) + (p2 + p3);
                pa[cb] = __builtin_bit_cast(short4v,
                          uint2{packbf2(p0, p1), packbf2(p2, p3)});
            }
            l_part[q2] += ls2;
#pragma unroll
            for (int kt = 0; kt < 4; kt++)
#pragma unroll
                for (int db = 0; db < 4; db++)
                    o_acc[q2][db] = __builtin_amdgcn_mfma_f32_16x16x16bf16_1k(
                        pa[kt], vb[kt][db], o_acc[q2][db], 0, 0, 0);
        }
    }

    // epilogue: finish l, normalize, store bf16, emit per-row (sum, sumsq)
    const int b = bh >> 4, h = bh & 15;
#pragma unroll
    for (int q2 = 0; q2 < 2; q2++) {
        float lr = l_part[q2];
        lr += __shfl_xor(lr, 16, 64);
        lr += __shfl_xor(lr, 32, 64);           // lanes now hold l(q = own l16)
#pragma unroll
        for (int r = 0; r < 4; r++) {
            const float lq = __shfl(lr, quad * 4 + r, 64);
            const float inv = 1.f / lq;
            const int rowl = q0 + w * 32 + q2 * 16 + quad * 4 + r;
            const int grow = b * 2048 + rowl;
            float s = 0.f, s2 = 0.f;
#pragma unroll
            for (int db = 0; db < 4; db++) {
                const float on = o_acc[q2][db][r] * inv;
                attn[(size_t)grow * 1024 + h * 64 + db * 16 + l16] = f2bf(on);
                s += on;
                s2 = fmaf(on, on, s2);
            }
#pragma unroll
            for (int off = 1; off <= 8; off <<= 1) {
                s  += __shfl_xor(s, off, 64);
                s2 += __shfl_xor(s2, off, 64);
            }
            if (l16 == 0) part[(size_t)grow * 16 + h] = float2{s, s2};
        }
    }
}

// ---------------- row stats for fused LN2: (rstd, mu*rstd) per output row
__global__ __launch_bounds__(256) void rowstats(const float2* __restrict__ part,
                                                float2* __restrict__ rowstat) {
    const int row = blockIdx.x * 256 + threadIdx.x;
    float s = 0.f, s2 = 0.f;
#pragma unroll
    for (int h = 0; h < 16; h++) {
        const float2 p = part[(size_t)row * 16 + h];
        s += p.x; s2 += p.y;
    }
    const float mu = s * (1.f / 1024.f);
    const float rstd = rsqrtf(s2 * (1.f / 1024.f) - mu * mu + 1e-5f);
    rowstat[row] = float2{rstd, mu * rstd};
}

// ---------------- GEMM2: attn(bf16,raw) @ Wg^T with LN2 fused in epilogue
__global__ __launch_bounds__(256) void gemm128_proj(const unsigned short* __restrict__ A,
                                                    const unsigned short* __restrict__ Bt,
                                                    const float2* __restrict__ rowstat,
                                                    const float* __restrict__ u,
                                                    const float* __restrict__ w0,
                                                    float* __restrict__ out) {
    __shared__ unsigned short As[128 * 64], Bs[128 * 64];
    const int m0 = blockIdx.y * 128, n0 = blockIdx.x * 128;
    float4v acc[4][4];
    gemm128_core(A, Bt, 1024, m0, n0, As, Bs, acc);
    const int lane = threadIdx.x & 63, w = threadIdx.x >> 6;
    const int wr = (w >> 1) * 64, wc = (w & 1) * 64;
    const int quad = lane >> 4, l16 = lane & 15;
#pragma unroll
    for (int mi = 0; mi < 4; mi++) {
        const int row0 = m0 + wr + mi * 16 + quad * 4;
        float2 rs[4];
#pragma unroll
        for (int r = 0; r < 4; r++) rs[r] = rowstat[row0 + r];
#pragma unroll
        for (int ni = 0; ni < 4; ni++) {
            const int col = n0 + wc + ni * 16 + l16;
            const float uu = u[col], ww = w0[col];
#pragma unroll
            for (int r = 0; r < 4; r++)
                out[(size_t)(row0 + r) * 1024 + col] =
                    fmaf(rs[r].x, acc[mi][ni][r], ww - rs[r].y * uu);
        }
    }
}

extern "C" void kernel_launch(void* const* d_in, const int* in_sizes, int n_in,
                              void* d_out, int out_size, void* d_ws, size_t ws_size,
                              hipStream_t stream) {
    const float* x      = (const float*)d_in[0];
    const float* ln1_g  = (const float*)d_in[1];
    const float* ln1_b  = (const float*)d_in[2];
    const float* w_qk   = (const float*)d_in[3];
    const float* w_v    = (const float*)d_in[4];
    const float* ln2_g  = (const float*)d_in[5];
    const float* ln2_b  = (const float*)d_in[6];
    const float* w_proj = (const float*)d_in[7];
    const float* b_proj = (const float*)d_in[8];
    float* out = (float*)d_out;

    char* ws = (char*)d_ws;
    unsigned short* xn      = (unsigned short*)(ws + 0);         // 8MB  4096x1024 bf16
    unsigned short* wqkvT   = (unsigned short*)(ws + 8388608);   // 6MB  3072x1024 bf16
    unsigned short* wgT     = (unsigned short*)(ws + 14680064);  // 2MB  1024x1024 bf16 (g2-scaled w_proj^T)
    unsigned short* qbuf    = (unsigned short*)(ws + 16777216);  // 8MB  [32][2048][64]
    unsigned short* kbuf    = (unsigned short*)(ws + 25165824);  // 8MB  [32][2048][64]
    unsigned short* vTbuf   = (unsigned short*)(ws + 33554432);  // 8MB  [32][64][2048]
    unsigned short* attn    = (unsigned short*)(ws + 41943040);  // 8MB  4096x1024 bf16 (raw, pre-LN2)
    float2*         part    = (float2*)(ws + 50331648);          // 512KB [4096][16]
    float2*         rowstat = (float2*)(ws + 50855936);          // 32KB  [4096]
    float*          u       = (float*)(ws + 50888704);           // 4KB
    float*          w0      = (float*)(ws + 50892800);           // 4KB

    prep<<<8196, 256, 0, stream>>>(x, ln1_g, ln1_b, w_qk, w_v, w_proj, ln2_g, ln2_b,
                                   b_proj, xn, wqkvT, wgT, u, w0);
    gemm128_qkv<<<dim3(24, 32), 256, 0, stream>>>(xn, wqkvT, qbuf, kbuf, vTbuf);
    flash_attn<<<dim3(16, 32), 256, 0, stream>>>(qbuf, kbuf, vTbuf, attn, part);
    rowstats<<<16, 256, 0, stream>>>(part, rowstat);
    gemm128_proj<<<dim3(8, 32), 256, 0, stream>>>(attn, wgT, rowstat, u, w0, out);
}

// Round 4
// 221.189 us; speedup vs baseline: 1.4607x; 1.1358x over previous
//
#include <hip/hip_runtime.h>
#include <hip/hip_bf16.h>

// B=2, N=2048, C=1024, H=16, hd=64, M=4096. bf16 MFMA path (threshold 2%).

typedef __attribute__((ext_vector_type(8))) short short8;
typedef __attribute__((ext_vector_type(4))) short short4v;
typedef __attribute__((ext_vector_type(4))) float float4v;

__device__ __forceinline__ unsigned short f2bf(float f) {   // RTNE
    unsigned u = __builtin_bit_cast(unsigned, f);
    return (unsigned short)((u + 0x7FFFu + ((u >> 16) & 1u)) >> 16);
}
// pack two f32 -> two bf16 (round-half-up) in one dword via v_perm
__device__ __forceinline__ unsigned packbf2(float lo, float hi) {
    return __builtin_amdgcn_perm(__builtin_bit_cast(unsigned, hi) + 0x8000u,
                                 __builtin_bit_cast(unsigned, lo) + 0x8000u,
                                 0x07060302u);
}
__device__ __forceinline__ void gll16(const unsigned short* g, unsigned short* l) {
    __builtin_amdgcn_global_load_lds(
        (const __attribute__((address_space(1))) unsigned int*)g,
        (__attribute__((address_space(3))) unsigned int*)l, 16, 0, 0);
}

// ---------------- prep: ln1 (blocks 0..4095) + weight transposes.
// wgT blocks also accumulate u[j] = sum_c g2[c]*Wp[c][j] and
// w0[j] = sum_c b2[c]*Wp[c][j] via in-register reduce + 1 atomicAdd/column.
__global__ __launch_bounds__(256) void prep(
    const float* __restrict__ x, const float* __restrict__ g1, const float* __restrict__ b1,
    const float* __restrict__ w_qk, const float* __restrict__ w_v,
    const float* __restrict__ w_proj, const float* __restrict__ g2,
    const float* __restrict__ b2,
    unsigned short* __restrict__ xn, unsigned short* __restrict__ wqkvT,
    unsigned short* __restrict__ wgT, float* __restrict__ u, float* __restrict__ w0) {
    __shared__ float sh[32 * 33];
    const int bid = blockIdx.x, tid = threadIdx.x;
    if (bid < 4096) {                       // ---- LN1 row
        const float4 v = reinterpret_cast<const float4*>(x + (size_t)bid * 1024)[tid];
        float s  = v.x + v.y + v.z + v.w;
        float sq = v.x * v.x + v.y * v.y + v.z * v.z + v.w * v.w;
#pragma unroll
        for (int off = 32; off >= 1; off >>= 1) {
            s  += __shfl_xor(s, off, 64);
            sq += __shfl_xor(sq, off, 64);
        }
        const int w = tid >> 6, lane = tid & 63;
        if (lane == 0) { sh[w] = s; sh[4 + w] = sq; }
        __syncthreads();
        s  = sh[0] + sh[1] + sh[2] + sh[3];
        sq = sh[4] + sh[5] + sh[6] + sh[7];
        const float mu = s * (1.f / 1024.f);
        const float rstd = rsqrtf(sq * (1.f / 1024.f) - mu * mu + 1e-5f);
        const float4 gv = reinterpret_cast<const float4*>(g1)[tid];
        const float4 bv = reinterpret_cast<const float4*>(b1)[tid];
        ushort4 o;
        o.x = f2bf((v.x - mu) * rstd * gv.x + bv.x);
        o.y = f2bf((v.y - mu) * rstd * gv.y + bv.y);
        o.z = f2bf((v.z - mu) * rstd * gv.z + bv.z);
        o.w = f2bf((v.w - mu) * rstd * gv.w + bv.w);
        *reinterpret_cast<ushort4*>(&xn[(size_t)bid * 1024 + tid * 4]) = o;
    } else {                                // ---- transpose f32[1024][Cc] -> bf16[Cc][1024]
        const float* in; unsigned short* out; int Cc, bx, by; bool doU = false;
        if (bid < 6144)      { int t = bid - 4096; in = w_qk;   out = wqkvT;               Cc = 2048; bx = t & 63; by = t >> 6; }
        else if (bid < 7168) { int t = bid - 6144; in = w_v;    out = wqkvT + 2048 * 1024; Cc = 1024; bx = t & 31; by = t >> 5; }
        else                 { int t = bid - 7168; in = w_proj; out = wgT; doU = true;     Cc = 1024; bx = t & 31; by = t >> 5; }
        const int c0 = bx * 32, r0 = by * 32;
        const int tx = tid & 31, ty = tid >> 5;
#pragma unroll
        for (int i = 0; i < 32; i += 8)
            sh[(ty + i) * 33 + tx] = in[(size_t)(r0 + ty + i) * Cc + c0 + tx];
        __syncthreads();
        // out col = original row index c = r0+tx
        const float scale = doU ? g2[r0 + tx] : 1.f;
        const float b2v   = doU ? b2[r0 + tx] : 0.f;
#pragma unroll
        for (int i = 0; i < 32; i += 8) {
            const float raw = sh[tx * 33 + ty + i];
            const float sc  = raw * scale;
            out[(size_t)(c0 + ty + i) * 1024 + r0 + tx] = f2bf(sc);
            if (doU) {
                float pu = sc, pw = raw * b2v;    // per-c contributions for j=c0+ty+i
#pragma unroll
                for (int off = 1; off <= 16; off <<= 1) {   // reduce over tx (32 lanes)
                    pu += __shfl_xor(pu, off, 64);
                    pw += __shfl_xor(pw, off, 64);
                }
                if (tx == 0) {
                    atomicAdd(&u[c0 + ty + i], pu);
                    atomicAdd(&w0[c0 + ty + i], pw);
                }
            }
        }
    }
}

// ---------------- 128x128 MFMA GEMM core (m97-style): A[M,K] x Bt[N,K]^T.
// global_load_lds width-16 staging into XOR-swizzled LDS [128][64].
__device__ __forceinline__ void gemm128_core(const unsigned short* __restrict__ A,
                                             const unsigned short* __restrict__ Bt,
                                             int K, int m0, int n0,
                                             unsigned short* As, unsigned short* Bs,
                                             float4v acc[4][4]) {
    const int tid = threadIdx.x, lane = tid & 63, w = tid >> 6;
    const int wr = (w >> 1) * 64, wc = (w & 1) * 64;
    const int quad = lane >> 4, l16 = lane & 15;
    const int ls = lane >> 3, sg = lane & 7;
#pragma unroll
    for (int mi = 0; mi < 4; mi++)
#pragma unroll
        for (int ni = 0; ni < 4; ni++) acc[mi][ni] = float4v{0.f, 0.f, 0.f, 0.f};

    for (int k0 = 0; k0 < K; k0 += 64) {
        __syncthreads();
#pragma unroll
        for (int i = 0; i < 4; i++) {
            const int r = w * 32 + i * 8 + ls;          // r&7 == ls
            const int g = (sg ^ ls) * 8;
            gll16(&A[(size_t)(m0 + r) * K + k0 + g], &As[(w * 32 + i * 8) * 64]);
            gll16(&Bt[(size_t)(n0 + r) * K + k0 + g], &Bs[(w * 32 + i * 8) * 64]);
        }
        __syncthreads();
#pragma unroll
        for (int ks = 0; ks < 2; ks++) {
            short8 af[4], bfr[4];
#pragma unroll
            for (int mi = 0; mi < 4; mi++) {
                const int r = wr + mi * 16 + l16;
                af[mi] = *reinterpret_cast<const short8*>(
                    &As[r * 64 + ((ks * 4 + quad) ^ (r & 7)) * 8]);
            }
#pragma unroll
            for (int ni = 0; ni < 4; ni++) {
                const int r = wc + ni * 16 + l16;
                bfr[ni] = *reinterpret_cast<const short8*>(
                    &Bs[r * 64 + ((ks * 4 + quad) ^ (r & 7)) * 8]);
            }
#pragma unroll
            for (int mi = 0; mi < 4; mi++)
#pragma unroll
                for (int ni = 0; ni < 4; ni++)
                    acc[mi][ni] = __builtin_amdgcn_mfma_f32_16x16x32_bf16(
                        af[mi], bfr[ni], acc[mi][ni], 0, 0, 0);
        }
    }
}

// ---------------- GEMM1: xn @ [w_qk|w_v]^T -> q (pre-scaled by 1/8*log2e), k, vT
__global__ __launch_bounds__(256) void gemm128_qkv(const unsigned short* __restrict__ A,
                                                   const unsigned short* __restrict__ Bt,
                                                   unsigned short* __restrict__ qb,
                                                   unsigned short* __restrict__ kb,
                                                   unsigned short* __restrict__ vT) {
    __shared__ unsigned short As[128 * 64], Bs[128 * 64];
    const int m0 = blockIdx.y * 128, n0 = blockIdx.x * 128;
    float4v acc[4][4];
    gemm128_core(A, Bt, 1024, m0, n0, As, Bs, acc);
    const int lane = threadIdx.x & 63, w = threadIdx.x >> 6;
    const int wr = (w >> 1) * 64, wc = (w & 1) * 64;
    const int quad = lane >> 4, l16 = lane & 15;
    const float QSCALE = 0.125f * 1.4426950408889634f;  // hd^-0.5 * log2(e)
#pragma unroll
    for (int mi = 0; mi < 4; mi++) {
        const int row0 = m0 + wr + mi * 16 + quad * 4;
        const int b = row0 >> 11, nq = row0 & 2047;
#pragma unroll
        for (int ni = 0; ni < 4; ni++) {
            const int col = n0 + wc + ni * 16 + l16;
            if (col < 1024) {             // q: [bh][n][d]
                const int h = col >> 6, d = col & 63;
#pragma unroll
                for (int r = 0; r < 4; r++)
                    qb[(((size_t)b * 16 + h) * 2048 + nq + r) * 64 + d] =
                        f2bf(acc[mi][ni][r] * QSCALE);
            } else if (col < 2048) {      // k: [bh][n][d]
                const int c = col - 1024, h = c >> 6, d = c & 63;
#pragma unroll
                for (int r = 0; r < 4; r++)
                    kb[(((size_t)b * 16 + h) * 2048 + nq + r) * 64 + d] = f2bf(acc[mi][ni][r]);
            } else {                      // v^T: [bh][d][n], 4 consecutive keys -> 8B store
                const int c = col - 2048, h = c >> 6, d = c & 63;
                const short4v sv = {(short)f2bf(acc[mi][ni][0]), (short)f2bf(acc[mi][ni][1]),
                                    (short)f2bf(acc[mi][ni][2]), (short)f2bf(acc[mi][ni][3])};
                *reinterpret_cast<short4v*>(
                    &vT[(((size_t)b * 16 + h) * 64 + d) * 2048 + nq]) = sv;
            }
        }
    }
}

// ---------------- flash attention v3: Q-tile 128 (32 q/wave), fixed-max softmax,
// S^T formulation, zero in-loop shuffles, swizzled conflict-free LDS.
__global__ __launch_bounds__(256) void flash_attn(const unsigned short* __restrict__ qbuf,
                                                  const unsigned short* __restrict__ kb,
                                                  const unsigned short* __restrict__ vT,
                                                  unsigned short* __restrict__ attn,
                                                  float2* __restrict__ part) {
    __shared__ unsigned short Ks[64 * 64];   // [key][d], XOR-swizzled 16B granules
    __shared__ unsigned short Vs[64 * 64];   // [d][key], XOR-swizzled 8B granules
    const int tid = threadIdx.x, lane = tid & 63, w = tid >> 6;
    const int quad = lane >> 4, l16 = lane & 15;
    const int ls = lane >> 3, sg = lane & 7;
    const int qt = blockIdx.x, bh = blockIdx.y;
    const int q0 = qt * 128;
    const size_t nbase = (size_t)bh * 2048;

    short8 bq[2][2];   // Q as B-operand for two 16-q subblocks
#pragma unroll
    for (int q2 = 0; q2 < 2; q2++)
#pragma unroll
        for (int ks = 0; ks < 2; ks++)
            bq[q2][ks] = *reinterpret_cast<const short8*>(
                &qbuf[(nbase + q0 + w * 32 + q2 * 16 + l16) * 64 + ks * 32 + quad * 8]);

    float l_part[2] = {0.f, 0.f};
    float4v o_acc[2][4];
#pragma unroll
    for (int q2 = 0; q2 < 2; q2++)
#pragma unroll
        for (int db = 0; db < 4; db++) o_acc[q2][db] = float4v{0.f, 0.f, 0.f, 0.f};

    for (int kt0 = 0; kt0 < 2048; kt0 += 64) {
        __syncthreads();
#pragma unroll
        for (int i = 0; i < 2; i++)
            gll16(&kb[(nbase + kt0 + w * 16 + i * 8 + ls) * 64 + ((sg ^ ls) << 3)],
                  &Ks[(w * 16 + i * 8) * 64]);
#pragma unroll
        for (int p = 0; p < 2; p++) {
            const int idx2 = p * 256 + tid;
            const int d = idx2 >> 3, G0 = (idx2 & 7) * 2;
            const uint4 vv = *reinterpret_cast<const uint4*>(
                &vT[((size_t)bh * 64 + d) * 2048 + kt0 + (G0 << 2)]);
            *reinterpret_cast<short4v*>(&Vs[(d << 6) + ((G0 ^ (d & 15)) << 2)]) =
                __builtin_bit_cast(short4v, uint2{vv.x, vv.y});
            *reinterpret_cast<short4v*>(&Vs[(d << 6) + (((G0 + 1) ^ (d & 15)) << 2)]) =
                __builtin_bit_cast(short4v, uint2{vv.z, vv.w});
        }
        __syncthreads();

        short8 kf[2][4];
#pragma unroll
        for (int ks = 0; ks < 2; ks++)
#pragma unroll
            for (int cb = 0; cb < 4; cb++) {
                const int r = cb * 16 + l16;
                kf[ks][cb] = *reinterpret_cast<const short8*>(
                    &Ks[r * 64 + ((ks * 4 + quad) ^ (r & 7)) * 8]);
            }
        short4v vb[4][4];
#pragma unroll
        for (int kt = 0; kt < 4; kt++)
#pragma unroll
            for (int db = 0; db < 4; db++)
                vb[kt][db] = *reinterpret_cast<const short4v*>(
                    &Vs[((db * 16 + l16) << 6) + (((kt * 4 + quad) ^ l16) << 2)]);

#pragma unroll
        for (int q2 = 0; q2 < 2; q2++) {
            float4v s_acc[4];
#pragma unroll
            for (int cb = 0; cb < 4; cb++) s_acc[cb] = float4v{0.f, 0.f, 0.f, 0.f};
#pragma unroll
            for (int ks = 0; ks < 2; ks++)
#pragma unroll
                for (int cb = 0; cb < 4; cb++)
                    s_acc[cb] = __builtin_amdgcn_mfma_f32_16x16x32_bf16(
                        kf[ks][cb], bq[q2][ks], s_acc[cb], 0, 0, 0);

            // fixed-max softmax: p = 2^s (s hard-bounded, O/l cancels)
            short4v pa[4];
            float ls2 = 0.f;
#pragma unroll
            for (int cb = 0; cb < 4; cb++) {
                const float p0 = __builtin_amdgcn_exp2f(s_acc[cb][0]);
                const float p1 = __builtin_amdgcn_exp2f(s_acc[cb][1]);
                const float p2 = __builtin_amdgcn_exp2f(s_acc[cb][2]);
                const float p3 = __builtin_amdgcn_exp2f(s_acc[cb][3]);
                ls2 += (p0 + p1) + (p2 + p3);
                pa[cb] = __builtin_bit_cast(short4v,
                          uint2{packbf2(p0, p1), packbf2(p2, p3)});
            }
            l_part[q2] += ls2;
#pragma unroll
            for (int kt = 0; kt < 4; kt++)
#pragma unroll
                for (int db = 0; db < 4; db++)
                    o_acc[q2][db] = __builtin_amdgcn_mfma_f32_16x16x16bf16_1k(
                        pa[kt], vb[kt][db], o_acc[q2][db], 0, 0, 0);
        }
    }

    // epilogue: finish l, normalize, store bf16, emit per-row (sum, sumsq)
    const int b = bh >> 4, h = bh & 15;
#pragma unroll
    for (int q2 = 0; q2 < 2; q2++) {
        float lr = l_part[q2];
        lr += __shfl_xor(lr, 16, 64);
        lr += __shfl_xor(lr, 32, 64);
#pragma unroll
        for (int r = 0; r < 4; r++) {
            const float lq = __shfl(lr, quad * 4 + r, 64);
            const float inv = 1.f / lq;
            const int rowl = q0 + w * 32 + q2 * 16 + quad * 4 + r;
            const int grow = b * 2048 + rowl;
            float s = 0.f, s2 = 0.f;
#pragma unroll
            for (int db = 0; db < 4; db++) {
                const float on = o_acc[q2][db][r] * inv;
                attn[(size_t)grow * 1024 + h * 64 + db * 16 + l16] = f2bf(on);
                s += on;
                s2 = fmaf(on, on, s2);
            }
#pragma unroll
            for (int off = 1; off <= 8; off <<= 1) {
                s  += __shfl_xor(s, off, 64);
                s2 += __shfl_xor(s2, off, 64);
            }
            if (l16 == 0) part[(size_t)grow * 16 + h] = float2{s, s2};
        }
    }
}

// ---------------- GEMM2: attn(bf16,raw) @ Wg^T, LN2 + rowstats fused in-kernel
__global__ __launch_bounds__(256) void gemm128_proj(const unsigned short* __restrict__ A,
                                                    const unsigned short* __restrict__ Bt,
                                                    const float2* __restrict__ part,
                                                    const float* __restrict__ u,
                                                    const float* __restrict__ w0,
                                                    const float* __restrict__ bias,
                                                    float* __restrict__ out) {
    __shared__ unsigned short As[128 * 64], Bs[128 * 64];
    __shared__ float2 rstat_s[128];
    const int m0 = blockIdx.y * 128, n0 = blockIdx.x * 128;
    {   // rowstats for this block's 128 rows: 2 threads/row, 8 heads each
        const int t = threadIdx.x, rloc = t >> 1, half = t & 1;
        const float4* p4 = reinterpret_cast<const float4*>(part);
        float s = 0.f, s2 = 0.f;
#pragma unroll
        for (int j = 0; j < 4; j++) {
            const float4 p = p4[(size_t)(m0 + rloc) * 8 + half * 4 + j];
            s += p.x + p.z; s2 += p.y + p.w;
        }
        s  += __shfl_xor(s, 1, 64);
        s2 += __shfl_xor(s2, 1, 64);
        if (!half) {
            const float mu = s * (1.f / 1024.f);
            const float rstd = rsqrtf(s2 * (1.f / 1024.f) - mu * mu + 1e-5f);
            rstat_s[rloc] = float2{rstd, mu * rstd};
        }
    }   // ordered before use by the core's internal __syncthreads()
    float4v acc[4][4];
    gemm128_core(A, Bt, 1024, m0, n0, As, Bs, acc);
    const int lane = threadIdx.x & 63, w = threadIdx.x >> 6;
    const int wr = (w >> 1) * 64, wc = (w & 1) * 64;
    const int quad = lane >> 4, l16 = lane & 15;
#pragma unroll
    for (int mi = 0; mi < 4; mi++) {
        const int rl0 = wr + mi * 16 + quad * 4;
        float2 rs[4];
#pragma unroll
        for (int r = 0; r < 4; r++) rs[r] = rstat_s[rl0 + r];
#pragma unroll
        for (int ni = 0; ni < 4; ni++) {
            const int col = n0 + wc + ni * 16 + l16;
            const float uu = u[col], ww = w0[col] + bias[col];
#pragma unroll
            for (int r = 0; r < 4; r++)
                out[(size_t)(m0 + rl0 + r) * 1024 + col] =
                    fmaf(rs[r].x, acc[mi][ni][r], ww - rs[r].y * uu);
        }
    }
}

extern "C" void kernel_launch(void* const* d_in, const int* in_sizes, int n_in,
                              void* d_out, int out_size, void* d_ws, size_t ws_size,
                              hipStream_t stream) {
    const float* x      = (const float*)d_in[0];
    const float* ln1_g  = (const float*)d_in[1];
    const float* ln1_b  = (const float*)d_in[2];
    const float* w_qk   = (const float*)d_in[3];
    const float* w_v    = (const float*)d_in[4];
    const float* ln2_g  = (const float*)d_in[5];
    const float* ln2_b  = (const float*)d_in[6];
    const float* w_proj = (const float*)d_in[7];
    const float* b_proj = (const float*)d_in[8];
    float* out = (float*)d_out;

    char* ws = (char*)d_ws;
    unsigned short* xn      = (unsigned short*)(ws + 0);         // 8MB  4096x1024 bf16
    unsigned short* wqkvT   = (unsigned short*)(ws + 8388608);   // 6MB  3072x1024 bf16
    unsigned short* wgT     = (unsigned short*)(ws + 14680064);  // 2MB  1024x1024 bf16 (g2-scaled w_proj^T)
    unsigned short* qbuf    = (unsigned short*)(ws + 16777216);  // 8MB  [32][2048][64]
    unsigned short* kbuf    = (unsigned short*)(ws + 25165824);  // 8MB  [32][2048][64]
    unsigned short* vTbuf   = (unsigned short*)(ws + 33554432);  // 8MB  [32][64][2048]
    unsigned short* attn    = (unsigned short*)(ws + 41943040);  // 8MB  4096x1024 bf16 (raw, pre-LN2)
    float2*         part    = (float2*)(ws + 50331648);          // 512KB [4096][16]
    float*          u       = (float*)(ws + 50888704);           // 4KB
    float*          w0      = (float*)(ws + 50892800);           // 4KB

    hipMemsetAsync(ws + 50888704, 0, 8192, stream);              // zero u + w0
    prep<<<8192, 256, 0, stream>>>(x, ln1_g, ln1_b, w_qk, w_v, w_proj, ln2_g, ln2_b,
                                   xn, wqkvT, wgT, u, w0);
    gemm128_qkv<<<dim3(24, 32), 256, 0, stream>>>(xn, wqkvT, qbuf, kbuf, vTbuf);
    flash_attn<<<dim3(16, 32), 256, 0, stream>>>(qbuf, kbuf, vTbuf, attn, part);
    gemm128_proj<<<dim3(8, 32), 256, 0, stream>>>(attn, wgT, part, u, w0, b_proj, out);
}

// Round 5
// 211.092 us; speedup vs baseline: 1.5306x; 1.0478x over previous
//
#include <hip/hip_runtime.h>
#include <hip/hip_bf16.h>

// B=2, N=2048, C=1024, H=16, hd=64, M=4096. bf16 MFMA path (threshold 2%).

typedef __attribute__((ext_vector_type(8))) short short8;
typedef __attribute__((ext_vector_type(4))) short short4v;
typedef __attribute__((ext_vector_type(4))) float float4v;

__device__ __forceinline__ unsigned short f2bf(float f) {   // RTNE
    unsigned u = __builtin_bit_cast(unsigned, f);
    return (unsigned short)((u + 0x7FFFu + ((u >> 16) & 1u)) >> 16);
}
// pack two f32 -> two bf16 (round-half-up) in one dword via v_perm
__device__ __forceinline__ unsigned packbf2(float lo, float hi) {
    return __builtin_amdgcn_perm(__builtin_bit_cast(unsigned, hi) + 0x8000u,
                                 __builtin_bit_cast(unsigned, lo) + 0x8000u,
                                 0x07060302u);
}
__device__ __forceinline__ void gll16(const unsigned short* g, unsigned short* l) {
    __builtin_amdgcn_global_load_lds(
        (const __attribute__((address_space(1))) unsigned int*)g,
        (__attribute__((address_space(3))) unsigned int*)l, 16, 0, 0);
}

// ---------------- prep: ln1 (blocks 0..4095) + weight transposes.
__global__ __launch_bounds__(256) void prep(
    const float* __restrict__ x, const float* __restrict__ g1, const float* __restrict__ b1,
    const float* __restrict__ w_qk, const float* __restrict__ w_v,
    const float* __restrict__ w_proj, const float* __restrict__ g2,
    const float* __restrict__ b2,
    unsigned short* __restrict__ xn, unsigned short* __restrict__ wqkvT,
    unsigned short* __restrict__ wgT, float* __restrict__ u, float* __restrict__ w0) {
    __shared__ float sh[32 * 33];
    const int bid = blockIdx.x, tid = threadIdx.x;
    if (bid < 4096) {                       // ---- LN1 row
        const float4 v = reinterpret_cast<const float4*>(x + (size_t)bid * 1024)[tid];
        float s  = v.x + v.y + v.z + v.w;
        float sq = v.x * v.x + v.y * v.y + v.z * v.z + v.w * v.w;
#pragma unroll
        for (int off = 32; off >= 1; off >>= 1) {
            s  += __shfl_xor(s, off, 64);
            sq += __shfl_xor(sq, off, 64);
        }
        const int w = tid >> 6, lane = tid & 63;
        if (lane == 0) { sh[w] = s; sh[4 + w] = sq; }
        __syncthreads();
        s  = sh[0] + sh[1] + sh[2] + sh[3];
        sq = sh[4] + sh[5] + sh[6] + sh[7];
        const float mu = s * (1.f / 1024.f);
        const float rstd = rsqrtf(sq * (1.f / 1024.f) - mu * mu + 1e-5f);
        const float4 gv = reinterpret_cast<const float4*>(g1)[tid];
        const float4 bv = reinterpret_cast<const float4*>(b1)[tid];
        ushort4 o;
        o.x = f2bf((v.x - mu) * rstd * gv.x + bv.x);
        o.y = f2bf((v.y - mu) * rstd * gv.y + bv.y);
        o.z = f2bf((v.z - mu) * rstd * gv.z + bv.z);
        o.w = f2bf((v.w - mu) * rstd * gv.w + bv.w);
        *reinterpret_cast<ushort4*>(&xn[(size_t)bid * 1024 + tid * 4]) = o;
    } else {                                // ---- transpose f32[1024][Cc] -> bf16[Cc][1024]
        const float* in; unsigned short* out; int Cc, bx, by; bool doU = false;
        if (bid < 6144)      { int t = bid - 4096; in = w_qk;   out = wqkvT;               Cc = 2048; bx = t & 63; by = t >> 6; }
        else if (bid < 7168) { int t = bid - 6144; in = w_v;    out = wqkvT + 2048 * 1024; Cc = 1024; bx = t & 31; by = t >> 5; }
        else                 { int t = bid - 7168; in = w_proj; out = wgT; doU = true;     Cc = 1024; bx = t & 31; by = t >> 5; }
        const int c0 = bx * 32, r0 = by * 32;
        const int tx = tid & 31, ty = tid >> 5;
#pragma unroll
        for (int i = 0; i < 32; i += 8)
            sh[(ty + i) * 33 + tx] = in[(size_t)(r0 + ty + i) * Cc + c0 + tx];
        __syncthreads();
        // out col = original row index c = r0+tx
        const float scale = doU ? g2[r0 + tx] : 1.f;
        const float b2v   = doU ? b2[r0 + tx] : 0.f;
#pragma unroll
        for (int i = 0; i < 32; i += 8) {
            const float raw = sh[tx * 33 + ty + i];
            const float sc  = raw * scale;
            out[(size_t)(c0 + ty + i) * 1024 + r0 + tx] = f2bf(sc);
            if (doU) {
                float pu = sc, pw = raw * b2v;    // per-c contributions for j=c0+ty+i
#pragma unroll
                for (int off = 1; off <= 16; off <<= 1) {   // reduce over tx (32 lanes)
                    pu += __shfl_xor(pu, off, 64);
                    pw += __shfl_xor(pw, off, 64);
                }
                if (tx == 0) {
                    atomicAdd(&u[c0 + ty + i], pu);
                    atomicAdd(&w0[c0 + ty + i], pw);
                }
            }
        }
    }
}

// ---------------- 128x128 MFMA GEMM core, DOUBLE-BUFFERED K-loop.
// One barrier per k-step: prefetch for step s+1 issued right after the
// barrier, drained at the NEXT barrier (after ~full compute time elapsed).
// LDS: As/Bs each 2 x [128][64] XOR-swizzled buffers (64 KB total).
__device__ __forceinline__ void stage_tiles(const unsigned short* __restrict__ A,
                                            const unsigned short* __restrict__ Bt,
                                            int K, int m0, int n0, int k0,
                                            unsigned short* As, unsigned short* Bs,
                                            int w, int ls, int sg) {
#pragma unroll
    for (int i = 0; i < 4; i++) {
        const int r = w * 32 + i * 8 + ls;          // r&7 == ls
        const int g = (sg ^ ls) * 8;
        gll16(&A[(size_t)(m0 + r) * K + k0 + g], &As[(w * 32 + i * 8) * 64]);
        gll16(&Bt[(size_t)(n0 + r) * K + k0 + g], &Bs[(w * 32 + i * 8) * 64]);
    }
}

__device__ __forceinline__ void gemm128_core(const unsigned short* __restrict__ A,
                                             const unsigned short* __restrict__ Bt,
                                             int K, int m0, int n0,
                                             unsigned short* As, unsigned short* Bs,
                                             float4v acc[4][4]) {
    const int tid = threadIdx.x, lane = tid & 63, w = tid >> 6;
    const int wr = (w >> 1) * 64, wc = (w & 1) * 64;
    const int quad = lane >> 4, l16 = lane & 15;
    const int ls = lane >> 3, sg = lane & 7;
#pragma unroll
    for (int mi = 0; mi < 4; mi++)
#pragma unroll
        for (int ni = 0; ni < 4; ni++) acc[mi][ni] = float4v{0.f, 0.f, 0.f, 0.f};

    const int NS = K >> 6;
    stage_tiles(A, Bt, K, m0, n0, 0, As, Bs, w, ls, sg);
    for (int s = 0; s < NS; s++) {
        __syncthreads();   // drains buf[s&1] loads; all waves done with buf[(s+1)&1]
        const int cur = (s & 1) << 13;               // *8192 shorts
        if (s + 1 < NS)
            stage_tiles(A, Bt, K, m0, n0, (s + 1) << 6,
                        As + (((s + 1) & 1) << 13), Bs + (((s + 1) & 1) << 13),
                        w, ls, sg);
        const unsigned short* Ac = As + cur;
        const unsigned short* Bc = Bs + cur;
#pragma unroll
        for (int ks = 0; ks < 2; ks++) {
            short8 af[4], bfr[4];
#pragma unroll
            for (int mi = 0; mi < 4; mi++) {
                const int r = wr + mi * 16 + l16;
                af[mi] = *reinterpret_cast<const short8*>(
                    &Ac[r * 64 + ((ks * 4 + quad) ^ (r & 7)) * 8]);
            }
#pragma unroll
            for (int ni = 0; ni < 4; ni++) {
                const int r = wc + ni * 16 + l16;
                bfr[ni] = *reinterpret_cast<const short8*>(
                    &Bc[r * 64 + ((ks * 4 + quad) ^ (r & 7)) * 8]);
            }
#pragma unroll
            for (int mi = 0; mi < 4; mi++)
#pragma unroll
                for (int ni = 0; ni < 4; ni++)
                    acc[mi][ni] = __builtin_amdgcn_mfma_f32_16x16x32_bf16(
                        af[mi], bfr[ni], acc[mi][ni], 0, 0, 0);
        }
    }
}

// ---------------- GEMM1: xn @ [w_qk|w_v]^T -> q (pre-scaled by 1/8*log2e), k, vT
__global__ __launch_bounds__(256) void gemm128_qkv(const unsigned short* __restrict__ A,
                                                   const unsigned short* __restrict__ Bt,
                                                   unsigned short* __restrict__ qb,
                                                   unsigned short* __restrict__ kb,
                                                   unsigned short* __restrict__ vT) {
    __shared__ unsigned short As[2 * 128 * 64], Bs[2 * 128 * 64];
    const int m0 = blockIdx.y * 128, n0 = blockIdx.x * 128;
    float4v acc[4][4];
    gemm128_core(A, Bt, 1024, m0, n0, As, Bs, acc);
    const int lane = threadIdx.x & 63, w = threadIdx.x >> 6;
    const int wr = (w >> 1) * 64, wc = (w & 1) * 64;
    const int quad = lane >> 4, l16 = lane & 15;
    const float QSCALE = 0.125f * 1.4426950408889634f;  // hd^-0.5 * log2(e)
#pragma unroll
    for (int mi = 0; mi < 4; mi++) {
        const int row0 = m0 + wr + mi * 16 + quad * 4;
        const int b = row0 >> 11, nq = row0 & 2047;
#pragma unroll
        for (int ni = 0; ni < 4; ni++) {
            const int col = n0 + wc + ni * 16 + l16;
            if (col < 1024) {             // q: [bh][n][d]
                const int h = col >> 6, d = col & 63;
#pragma unroll
                for (int r = 0; r < 4; r++)
                    qb[(((size_t)b * 16 + h) * 2048 + nq + r) * 64 + d] =
                        f2bf(acc[mi][ni][r] * QSCALE);
            } else if (col < 2048) {      // k: [bh][n][d]
                const int c = col - 1024, h = c >> 6, d = c & 63;
#pragma unroll
                for (int r = 0; r < 4; r++)
                    kb[(((size_t)b * 16 + h) * 2048 + nq + r) * 64 + d] = f2bf(acc[mi][ni][r]);
            } else {                      // v^T: [bh][d][n], 4 consecutive keys -> 8B store
                const int c = col - 2048, h = c >> 6, d = c & 63;
                const short4v sv = {(short)f2bf(acc[mi][ni][0]), (short)f2bf(acc[mi][ni][1]),
                                    (short)f2bf(acc[mi][ni][2]), (short)f2bf(acc[mi][ni][3])};
                *reinterpret_cast<short4v*>(
                    &vT[(((size_t)b * 16 + h) * 64 + d) * 2048 + nq]) = sv;
            }
        }
    }
}

// ---------------- flash attention v3: Q-tile 128 (32 q/wave), fixed-max softmax,
// S^T formulation, zero in-loop shuffles, swizzled conflict-free LDS.
__global__ __launch_bounds__(256) void flash_attn(const unsigned short* __restrict__ qbuf,
                                                  const unsigned short* __restrict__ kb,
                                                  const unsigned short* __restrict__ vT,
                                                  unsigned short* __restrict__ attn,
                                                  float2* __restrict__ part) {
    __shared__ unsigned short Ks[64 * 64];   // [key][d], XOR-swizzled 16B granules
    __shared__ unsigned short Vs[64 * 64];   // [d][key], XOR-swizzled 8B granules
    const int tid = threadIdx.x, lane = tid & 63, w = tid >> 6;
    const int quad = lane >> 4, l16 = lane & 15;
    const int ls = lane >> 3, sg = lane & 7;
    const int qt = blockIdx.x, bh = blockIdx.y;
    const int q0 = qt * 128;
    const size_t nbase = (size_t)bh * 2048;

    short8 bq[2][2];   // Q as B-operand for two 16-q subblocks
#pragma unroll
    for (int q2 = 0; q2 < 2; q2++)
#pragma unroll
        for (int ks = 0; ks < 2; ks++)
            bq[q2][ks] = *reinterpret_cast<const short8*>(
                &qbuf[(nbase + q0 + w * 32 + q2 * 16 + l16) * 64 + ks * 32 + quad * 8]);

    float l_part[2] = {0.f, 0.f};
    float4v o_acc[2][4];
#pragma unroll
    for (int q2 = 0; q2 < 2; q2++)
#pragma unroll
        for (int db = 0; db < 4; db++) o_acc[q2][db] = float4v{0.f, 0.f, 0.f, 0.f};

    for (int kt0 = 0; kt0 < 2048; kt0 += 64) {
        __syncthreads();
#pragma unroll
        for (int i = 0; i < 2; i++)
            gll16(&kb[(nbase + kt0 + w * 16 + i * 8 + ls) * 64 + ((sg ^ ls) << 3)],
                  &Ks[(w * 16 + i * 8) * 64]);
#pragma unroll
        for (int p = 0; p < 2; p++) {
            const int idx2 = p * 256 + tid;
            const int d = idx2 >> 3, G0 = (idx2 & 7) * 2;
            const uint4 vv = *reinterpret_cast<const uint4*>(
                &vT[((size_t)bh * 64 + d) * 2048 + kt0 + (G0 << 2)]);
            *reinterpret_cast<short4v*>(&Vs[(d << 6) + ((G0 ^ (d & 15)) << 2)]) =
                __builtin_bit_cast(short4v, uint2{vv.x, vv.y});
            *reinterpret_cast<short4v*>(&Vs[(d << 6) + (((G0 + 1) ^ (d & 15)) << 2)]) =
                __builtin_bit_cast(short4v, uint2{vv.z, vv.w});
        }
        __syncthreads();

        short8 kf[2][4];
#pragma unroll
        for (int ks = 0; ks < 2; ks++)
#pragma unroll
            for (int cb = 0; cb < 4; cb++) {
                const int r = cb * 16 + l16;
                kf[ks][cb] = *reinterpret_cast<const short8*>(
                    &Ks[r * 64 + ((ks * 4 + quad) ^ (r & 7)) * 8]);
            }
        short4v vb[4][4];
#pragma unroll
        for (int kt = 0; kt < 4; kt++)
#pragma unroll
            for (int db = 0; db < 4; db++)
                vb[kt][db] = *reinterpret_cast<const short4v*>(
                    &Vs[((db * 16 + l16) << 6) + (((kt * 4 + quad) ^ l16) << 2)]);

#pragma unroll
        for (int q2 = 0; q2 < 2; q2++) {
            float4v s_acc[4];
#pragma unroll
            for (int cb = 0; cb < 4; cb++) s_acc[cb] = float4v{0.f, 0.f, 0.f, 0.f};
#pragma unroll
            for (int ks = 0; ks < 2; ks++)
#pragma unroll
                for (int cb = 0; cb < 4; cb++)
                    s_acc[cb] = __builtin_amdgcn_mfma_f32_16x16x32_bf16(
                        kf[ks][cb], bq[q2][ks], s_acc[cb], 0, 0, 0);

            // fixed-max softmax: p = 2^s (s hard-bounded, O/l cancels)
            short4v pa[4];
            float ls2 = 0.f;
#pragma unroll
            for (int cb = 0; cb < 4; cb++) {
                const float p0 = __builtin_amdgcn_exp2f(s_acc[cb][0]);
                const float p1 = __builtin_amdgcn_exp2f(s_acc[cb][1]);
                const float p2 = __builtin_amdgcn_exp2f(s_acc[cb][2]);
                const float p3 = __builtin_amdgcn_exp2f(s_acc[cb][3]);
                ls2 += (p0 + p1) + (p2 + p3);
                pa[cb] = __builtin_bit_cast(short4v,
                          uint2{packbf2(p0, p1), packbf2(p2, p3)});
            }
            l_part[q2] += ls2;
#pragma unroll
            for (int kt = 0; kt < 4; kt++)
#pragma unroll
                for (int db = 0; db < 4; db++)
                    o_acc[q2][db] = __builtin_amdgcn_mfma_f32_16x16x16bf16_1k(
                        pa[kt], vb[kt][db], o_acc[q2][db], 0, 0, 0);
        }
    }

    // epilogue: finish l, normalize, store bf16, emit per-row (sum, sumsq)
    const int b = bh >> 4, h = bh & 15;
#pragma unroll
    for (int q2 = 0; q2 < 2; q2++) {
        float lr = l_part[q2];
        lr += __shfl_xor(lr, 16, 64);
        lr += __shfl_xor(lr, 32, 64);
#pragma unroll
        for (int r = 0; r < 4; r++) {
            const float lq = __shfl(lr, quad * 4 + r, 64);
            const float inv = 1.f / lq;
            const int rowl = q0 + w * 32 + q2 * 16 + quad * 4 + r;
            const int grow = b * 2048 + rowl;
            float s = 0.f, s2 = 0.f;
#pragma unroll
            for (int db = 0; db < 4; db++) {
                const float on = o_acc[q2][db][r] * inv;
                attn[(size_t)grow * 1024 + h * 64 + db * 16 + l16] = f2bf(on);
                s += on;
                s2 = fmaf(on, on, s2);
            }
#pragma unroll
            for (int off = 1; off <= 8; off <<= 1) {
                s  += __shfl_xor(s, off, 64);
                s2 += __shfl_xor(s2, off, 64);
            }
            if (l16 == 0) part[(size_t)grow * 16 + h] = float2{s, s2};
        }
    }
}

// ---------------- GEMM2: attn(bf16,raw) @ Wg^T, LN2 + rowstats fused in-kernel
__global__ __launch_bounds__(256) void gemm128_proj(const unsigned short* __restrict__ A,
                                                    const unsigned short* __restrict__ Bt,
                                                    const float2* __restrict__ part,
                                                    const float* __restrict__ u,
                                                    const float* __restrict__ w0,
                                                    const float* __restrict__ bias,
                                                    float* __restrict__ out) {
    __shared__ unsigned short As[2 * 128 * 64], Bs[2 * 128 * 64];
    __shared__ float2 rstat_s[128];
    const int m0 = blockIdx.y * 128, n0 = blockIdx.x * 128;
    {   // rowstats for this block's 128 rows: 2 threads/row, 8 heads each
        const int t = threadIdx.x, rloc = t >> 1, half = t & 1;
        const float4* p4 = reinterpret_cast<const float4*>(part);
        float s = 0.f, s2 = 0.f;
#pragma unroll
        for (int j = 0; j < 4; j++) {
            const float4 p = p4[(size_t)(m0 + rloc) * 8 + half * 4 + j];
            s += p.x + p.z; s2 += p.y + p.w;
        }
        s  += __shfl_xor(s, 1, 64);
        s2 += __shfl_xor(s2, 1, 64);
        if (!half) {
            const float mu = s * (1.f / 1024.f);
            const float rstd = rsqrtf(s2 * (1.f / 1024.f) - mu * mu + 1e-5f);
            rstat_s[rloc] = float2{rstd, mu * rstd};
        }
    }   // ordered before use by the core's internal __syncthreads()
    float4v acc[4][4];
    gemm128_core(A, Bt, 1024, m0, n0, As, Bs, acc);
    const int lane = threadIdx.x & 63, w = threadIdx.x >> 6;
    const int wr = (w >> 1) * 64, wc = (w & 1) * 64;
    const int quad = lane >> 4, l16 = lane & 15;
#pragma unroll
    for (int mi = 0; mi < 4; mi++) {
        const int rl0 = wr + mi * 16 + quad * 4;
        float2 rs[4];
#pragma unroll
        for (int r = 0; r < 4; r++) rs[r] = rstat_s[rl0 + r];
#pragma unroll
        for (int ni = 0; ni < 4; ni++) {
            const int col = n0 + wc + ni * 16 + l16;
            const float uu = u[col], ww = w0[col] + bias[col];
#pragma unroll
            for (int r = 0; r < 4; r++)
                out[(size_t)(m0 + rl0 + r) * 1024 + col] =
                    fmaf(rs[r].x, acc[mi][ni][r], ww - rs[r].y * uu);
        }
    }
}

extern "C" void kernel_launch(void* const* d_in, const int* in_sizes, int n_in,
                              void* d_out, int out_size, void* d_ws, size_t ws_size,
                              hipStream_t stream) {
    const float* x      = (const float*)d_in[0];
    const float* ln1_g  = (const float*)d_in[1];
    const float* ln1_b  = (const float*)d_in[2];
    const float* w_qk   = (const float*)d_in[3];
    const float* w_v    = (const float*)d_in[4];
    const float* ln2_g  = (const float*)d_in[5];
    const float* ln2_b  = (const float*)d_in[6];
    const float* w_proj = (const float*)d_in[7];
    const float* b_proj = (const float*)d_in[8];
    float* out = (float*)d_out;

    char* ws = (char*)d_ws;
    unsigned short* xn      = (unsigned short*)(ws + 0);         // 8MB  4096x1024 bf16
    unsigned short* wqkvT   = (unsigned short*)(ws + 8388608);   // 6MB  3072x1024 bf16
    unsigned short* wgT     = (unsigned short*)(ws + 14680064);  // 2MB  1024x1024 bf16 (g2-scaled w_proj^T)
    unsigned short* qbuf    = (unsigned short*)(ws + 16777216);  // 8MB  [32][2048][64]
    unsigned short* kbuf    = (unsigned short*)(ws + 25165824);  // 8MB  [32][2048][64]
    unsigned short* vTbuf   = (unsigned short*)(ws + 33554432);  // 8MB  [32][64][2048]
    unsigned short* attn    = (unsigned short*)(ws + 41943040);  // 8MB  4096x1024 bf16 (raw, pre-LN2)
    float2*         part    = (float2*)(ws + 50331648);          // 512KB [4096][16]
    float*          u       = (float*)(ws + 50888704);           // 4KB
    float*          w0      = (float*)(ws + 50892800);           // 4KB

    hipMemsetAsync(ws + 50888704, 0, 8192, stream);              // zero u + w0
    prep<<<8192, 256, 0, stream>>>(x, ln1_g, ln1_b, w_qk, w_v, w_proj, ln2_g, ln2_b,
                                   xn, wqkvT, wgT, u, w0);
    gemm128_qkv<<<dim3(24, 32), 256, 0, stream>>>(xn, wqkvT, qbuf, kbuf, vTbuf);
    flash_attn<<<dim3(16, 32), 256, 0, stream>>>(qbuf, kbuf, vTbuf, attn, part);
    gemm128_proj<<<dim3(8, 32), 256, 0, stream>>>(attn, wgT, part, u, w0, b_proj, out);
}